// Round 4
// baseline (1865.145 us; speedup 1.0000x reference)
//
#include <hip/hip_runtime.h>

// DA-RNN fused — R12: 1024-thread block DESIGNED for the 64-VGPR cap.
//  * R11 post-mortem: 16 waves/CU achieved (occ 47%) but backend caps 1024-thr
//    blocks at VGPR=64 -> wpkD[64]/wq[64]/wtp[64] spilled (FETCH 1.4 GB).
//  * R12: lane-pair K-split on every big GEMM: thread (row=tid>>1, kh=tid&1)
//    holds HALF a weight row (32 u32), half-dot + __shfl_xor(g,1) combine
//    (in-wave, no barrier, no LDS). Applied to Q GEMM, encoder gates, E1,
//    decoder S6. Peak live set ~60 regs -> no spills at cap 64.
//  * S3 all-4-batch wave-redundant (R8-proven); S0/S1/S2/ye/alpha/ctx as R11.
//  * Weight-vector LDS reads are wave-uniform broadcasts (cheap); E1/encoder
//    read Xe/Q from workspace via L2.

typedef unsigned int   u32;
typedef unsigned short u16;

#define T_   100
#define C_   32
#define NT   1024
#define NTF  512
#define BPB  4
#define TS   132
#define QROW 512
#define QS   (T_ * QROW)

typedef __attribute__((ext_vector_type(2))) __fp16 h16x2;

#if __has_builtin(__builtin_amdgcn_fdot2)
#define HAVE_FDOT2 1
#else
#define HAVE_FDOT2 0
#endif

__device__ __forceinline__ u32 pkh2(float a, float b) {
#if __has_builtin(__builtin_amdgcn_cvt_pkrtz)
  h16x2 p = __builtin_amdgcn_cvt_pkrtz(a, b);
  return __builtin_bit_cast(u32, p);
#else
  union { __fp16 h[2]; u32 u; } v;
  v.h[0] = (__fp16)a; v.h[1] = (__fp16)b;
  return v.u;
#endif
}
__device__ __forceinline__ void unph(u32 p, float& lo, float& hi) {
  union { u32 u; __fp16 h[2]; } v; v.u = p;
  lo = (float)v.h[0]; hi = (float)v.h[1];
}
__device__ __forceinline__ u16 f2h(float f) {
  union { __fp16 h; u16 u; } v; v.h = (__fp16)f; return v.u;
}
__device__ __forceinline__ float h2f(u16 u) {
  union { u16 u; __fp16 h; } v; v.u = u; return (float)v.h;
}
__device__ __forceinline__ float dot2h(u32 w, u32 x, float acc) {
#if HAVE_FDOT2
  return __builtin_amdgcn_fdot2(__builtin_bit_cast(h16x2, w),
                                __builtin_bit_cast(h16x2, x),
                                acc, false);
#else
  float a, b, c, d;
  unph(w, a, b); unph(x, c, d);
  return fmaf(a, c, fmaf(b, d, acc));
#endif
}

#if __has_builtin(__builtin_amdgcn_rcpf)
__device__ __forceinline__ float rcpf_(float x){ return __builtin_amdgcn_rcpf(x); }
#else
__device__ __forceinline__ float rcpf_(float x){ return 1.0f / x; }
#endif
__device__ __forceinline__ float sigm(float x){ return rcpf_(1.0f + __expf(-x)); }
__device__ __forceinline__ float tanh_(float x){
  return 1.0f - 2.0f * rcpf_(1.0f + __expf(2.0f * x));
}
__device__ __forceinline__ float ptanh(float x){
  x = fminf(1.0f, fmaxf(-1.0f, x));
  float x2 = x * x;
  float p  = fmaf(x2, 0.1333333f, -0.3333333f);
  return x * fmaf(x2, p, 1.0f);
}
__device__ __forceinline__ float wsum(float v){
  #pragma unroll
  for (int o = 32; o; o >>= 1) v += __shfl_xor(v, o, 64);
  return v;
}

// ==================== fast kernel (4 batches, 1024 threads) =================
__global__ void __launch_bounds__(NT)
darnn4(const float* __restrict__ X,
       const float* __restrict__ eWih, const float* __restrict__ eWhh,
       const float* __restrict__ ebih, const float* __restrict__ ebhh,
       const float* __restrict__ eAw,  const float* __restrict__ eAb,
       const float* __restrict__ dW1,  const float* __restrict__ db1,
       const float* __restrict__ dW2,  const float* __restrict__ db2,
       const float* __restrict__ dWih, const float* __restrict__ dWhh,
       const float* __restrict__ dbih, const float* __restrict__ dbhh,
       const float* __restrict__ fcW,  const float* __restrict__ fcb,
       const float* __restrict__ fcfW, const float* __restrict__ fcfb,
       u16* __restrict__ qws,
       float* __restrict__ out)
{
  // LDS ~137.7 KB, one block/CU
  __shared__ __align__(16) u16   sE1[BPB][T_ * TS];   // 105600
  __shared__ __align__(16) float sg[BPB][512];        //   8192
  __shared__ __align__(16) float sh[BPB][128];        //   2048
  __shared__ __align__(16) float sc[BPB][128];        //   2048
  __shared__ __align__(16) u16   shp[BPB][128];       //   1024
  __shared__ __align__(16) u16   scp[BPB][128];       //   1024
  __shared__ __align__(16) float su[BPB][128];        //   2048
  __shared__ __align__(16) float spart[BPB][1024];    //  16384
  __shared__ __align__(16) float sye[BPB][128];       //   2048
  __shared__ __align__(16) float sw2[128];            //    512
  __shared__ float sred[16];

  const int tid  = threadIdx.x;
  const int lane = tid & 63;
  const int wv   = tid >> 6;     // 0..15
  const int hh   = tid & 127;
  const int oct  = tid >> 7;     // 0..7 (column-eighth)
  const int quad = oct & 3;      // batch idx on tid<512 paths
  const int kh   = tid & 1;      // K-half for lane-pair split
  const int row2 = tid >> 1;     // 0..511 gate row / slot
  const int b0   = blockIdx.x * BPB;

  (void)eAb; (void)db2;          // cancel under softmax shift-invariance

  if (tid < 128) sw2[tid] = dW2[tid];

  // ---------- alpha (h/c terms cancel) + x_tilde (tid<512) ----------
  {
    const float* xp = X + (size_t)(b0 + quad) * 12800 + hh;
    if (tid < 512) {
      float sval = 0.f;
      #pragma unroll 4
      for (int t = 0; t < T_; ++t) sval += xp[t * 128] * eAw[256 + t];
      float e = __expf(sval);
      float s = wsum(e);
      if (lane == 0) sred[wv] = s;
      spart[quad][hh] = e;               // stash e across the barrier
    }
    __syncthreads();
    if (tid < 512) {
      float e  = spart[quad][hh];
      float al = e * rcpf_(sred[quad * 2] + sred[quad * 2 + 1]);
      #pragma unroll 4
      for (int t = 0; t < T_; ++t)
        sE1[quad][t * TS + hh] = f2h(al * xp[t * 128]);
      sh[quad][hh] = 0.f; sc[quad][hh] = 0.f;
      shp[quad][hh] = 0;  scp[quad][hh] = 0;
    }
  }
  __syncthreads();

  // ---------- Q GEMM: Q[b][t][r] = eWih[r,:]·x_tilde (lane-pair K-split) ----
  {
    u32 wqh[32];   // eWih[row2][kh*64 .. +64)
    const float4* wi = (const float4*)(eWih + (size_t)row2 * 128 + kh * 64);
    #pragma unroll
    for (int i = 0; i < 16; ++i) {
      float4 v = wi[i];
      wqh[2*i]   = pkh2(v.x, v.y);
      wqh[2*i+1] = pkh2(v.z, v.w);
    }
    #pragma unroll 1
    for (int bg = 0; bg < BPB; ++bg) {
      u16* qb = qws + (size_t)(b0 + bg) * QS;
      #pragma unroll 1
      for (int t = 0; t < T_; ++t) {
        const uint2* xr = (const uint2*)(&sE1[bg][t * TS + kh * 64]);
        float a0 = 0.f, a1 = 0.f;
        #pragma unroll
        for (int k = 0; k < 16; ++k) {
          uint2 xv = xr[k];
          a0 = dot2h(wqh[2*k],   xv.x, a0);
          a1 = dot2h(wqh[2*k+1], xv.y, a1);
        }
        float g = a0 + a1;
        g += __shfl_xor(g, 1, 64);
        if (kh == 0) qb[t * QROW + row2] = f2h(g);
      }
    }
  }
  __syncthreads();   // Q visible to all

  // ---------- encoder (2 barriers/step; lane-pair K-split, 4 bg) ----------
  {
    u32 wpkHh[32];   // eWhh[row2][kh*64 .. +64)
    const float4* wr = (const float4*)(eWhh + (size_t)row2 * 128 + kh * 64);
    #pragma unroll
    for (int i = 0; i < 16; ++i) {
      float4 v = wr[i];
      wpkHh[2*i]   = pkh2(v.x, v.y);
      wpkHh[2*i+1] = pkh2(v.z, v.w);
    }
    float biasg = ebih[row2] + ebhh[row2];

    u16 qc[BPB];
    #pragma unroll
    for (int bg = 0; bg < BPB; ++bg)
      qc[bg] = qws[(size_t)(b0 + bg) * QS + row2];

    for (int t = 0; t < T_; ++t) {
      u16 qn[BPB];
      #pragma unroll
      for (int bg = 0; bg < BPB; ++bg)
        qn[bg] = (t + 1 < T_)
               ? qws[(size_t)(b0 + bg) * QS + (t + 1) * QROW + row2]
               : (u16)0;
      #pragma unroll
      for (int bg = 0; bg < BPB; ++bg) {
        const uint4* hr = (const uint4*)((const u32*)shp[bg] + kh * 32);
        float a0 = 0.f, a1 = 0.f, a2 = 0.f, a3 = 0.f;
        #pragma unroll
        for (int k = 0; k < 8; ++k) {
          uint4 hv = hr[k];
          a0 = dot2h(wpkHh[4*k+0], hv.x, a0);
          a1 = dot2h(wpkHh[4*k+1], hv.y, a1);
          a2 = dot2h(wpkHh[4*k+2], hv.z, a2);
          a3 = dot2h(wpkHh[4*k+3], hv.w, a3);
        }
        float g = (a0 + a1) + (a2 + a3);
        g += __shfl_xor(g, 1, 64);
        if (kh == 0) sg[bg][row2] = g + biasg + h2f(qc[bg]);
      }
      __syncthreads();
      if (tid < 512) {
        float gi = sigm(sg[quad][hh]);
        float gf = sigm(sg[quad][hh + 128]);
        float gg = tanh_(sg[quad][hh + 256]);
        float go = sigm(sg[quad][hh + 384]);
        float c  = gf * sc[quad][hh] + gi * gg;
        sc[quad][hh] = c;
        float h  = go * tanh_(c);
        sh[quad][hh] = h;
        u16 hb = f2h(h);
        shp[quad][hh] = hb;
        scp[quad][hh] = f2h(c);
        // Xe row t shares Q's slab (Q[t] already consumed; barrier-ordered)
        qws[(size_t)(b0 + quad) * QS + t * QROW + hh] = hb;
      }
      __syncthreads();
      #pragma unroll
      for (int bg = 0; bg < BPB; ++bg) qc[bg] = qn[bg];
    }
  }

  // ---------- ye[t] = fcW · Xe[t]  (oct-split partials) ----------
  if (hh < T_) {
    #pragma unroll 1
    for (int bg = 0; bg < BPB; ++bg) {
      const uint2* xe = (const uint2*)(qws + (size_t)(b0 + bg) * QS
                                       + hh * QROW + oct * 16);
      const float* fw = fcW + oct * 16;
      float a = 0.f;
      #pragma unroll
      for (int k = 0; k < 4; ++k) {
        uint2 xv = xe[k];
        float l0, l1, l2, l3;
        unph(xv.x, l0, l1); unph(xv.y, l2, l3);
        a += fw[4*k]*l0 + fw[4*k+1]*l1 + fw[4*k+2]*l2 + fw[4*k+3]*l3;
      }
      spart[bg][oct * 128 + hh] = a;
    }
  }
  __syncthreads();
  if (tid < 512 && hh < T_) {
    float a = spart[quad][hh]       + spart[quad][128 + hh]
            + spart[quad][256 + hh] + spart[quad][384 + hh]
            + spart[quad][512 + hh] + spart[quad][640 + hh]
            + spart[quad][768 + hh] + spart[quad][896 + hh];
    sye[quad][hh] = a;
  }
  __syncthreads();

  // ---- E1[t][h] = dW1[h][256:384]·Xe[t] + db1[h] (lane-pair K-split) ----
  {
    const int tg = row2 >> 7;        // 0..3 (25-t chunk)
    const int h  = row2 & 127;
    u32 wtph[32];   // dW1[h][256 + kh*64 .. +64)
    const float4* w4p = (const float4*)(dW1 + (size_t)h * 384 + 256 + kh * 64);
    #pragma unroll
    for (int i = 0; i < 16; ++i) {
      float4 v = w4p[i];
      wtph[2*i]   = pkh2(v.x, v.y);
      wtph[2*i+1] = pkh2(v.z, v.w);
    }
    float b1v = db1[h];
    #pragma unroll 1
    for (int bg = 0; bg < BPB; ++bg) {
      const u16* xb = qws + (size_t)(b0 + bg) * QS;
      #pragma unroll 1
      for (int i = 0; i < 25; ++i) {
        const int t = tg * 25 + i;
        const uint2* xe = (const uint2*)(xb + t * QROW + kh * 64);
        float a0 = 0.f, a1 = 0.f;
        #pragma unroll
        for (int k = 0; k < 16; ++k) {
          uint2 xv = xe[k];
          a0 = dot2h(wtph[2*k],   xv.x, a0);
          a1 = dot2h(wtph[2*k+1], xv.y, a1);
        }
        float g = a0 + a1;
        g += __shfl_xor(g, 1, 64);
        if (kh == 0) sE1[bg][t * TS + h] = f2h(g + b1v);
      }
    }
  }

  // ---------- decoder weights (lane-pair halves) ----------
  u32 wpkDh[32];   // dWhh[row2][kh*64 .. +64)
  {
    const float4* wr = (const float4*)(dWhh + (size_t)row2 * 128 + kh * 64);
    #pragma unroll
    for (int i = 0; i < 16; ++i) {
      float4 v = wr[i];
      wpkDh[2*i]   = pkh2(v.x, v.y);
      wpkDh[2*i+1] = pkh2(v.z, v.w);
    }
  }
  u32 wtpU[16];   // dW1 row hh, z-cols [oct*32, oct*32+32)
  {
    const float4* wu = (const float4*)(dW1 + (size_t)hh * 384 + oct * 32);
    #pragma unroll
    for (int i = 0; i < 8; ++i) {
      float4 v = wu[i];
      wtpU[2*i]   = pkh2(v.x, v.y);
      wtpU[2*i+1] = pkh2(v.z, v.w);
    }
  }
  float biasD = dbih[row2] + dbhh[row2];
  float wihj  = dWih[row2];
  float fcbv  = fcb[0];
  if (tid < 512) {
    sh[quad][hh] = 0.f; sc[quad][hh] = 0.f;
    shp[quad][hh] = 0;  scp[quad][hh] = 0;
  }
  __syncthreads();

  // ---------- decoder (5 barriers/step) ----------
  for (int step = 0; step < T_; ++step) {
    // S0: u partials over z=[d;c] cols oct*32..+32, all batches
    #pragma unroll 1
    for (int bg = 0; bg < BPB; ++bg) {
      const u32* bs = (oct < 4) ? (const u32*)shp[bg] + oct * 16
                                : (const u32*)scp[bg] + (oct - 4) * 16;
      const uint4* vp = (const uint4*)bs;
      float a0 = 0.f, a1 = 0.f;
      #pragma unroll
      for (int k = 0; k < 4; ++k) {
        uint4 v = vp[k];
        a0 = dot2h(wtpU[4*k+0], v.x, a0);
        a1 = dot2h(wtpU[4*k+1], v.y, a1);
        a0 = dot2h(wtpU[4*k+2], v.z, a0);
        a1 = dot2h(wtpU[4*k+3], v.w, a1);
      }
      spart[bg][oct * 128 + hh] = a0 + a1;
    }
    __syncthreads();
    // S1: reduce u (tid<512)
    if (tid < 512) {
      float a = spart[quad][hh]       + spart[quad][128 + hh]
              + spart[quad][256 + hh] + spart[quad][384 + hh]
              + spart[quad][512 + hh] + spart[quad][640 + hh]
              + spart[quad][768 + hh] + spart[quad][896 + hh];
      su[quad][hh] = a;
    }
    __syncthreads();
    // S2: score partials: thread (t=hh<100, oct), 16 h each
    if (hh < T_) {
      #pragma unroll 1
      for (int bg = 0; bg < BPB; ++bg) {
        const uint2*  ep = (const uint2*)(&sE1[bg][hh * TS + oct * 16]);
        const float4* up = (const float4*)(&su[bg][oct * 16]);
        const float4* wp = (const float4*)(&sw2[oct * 16]);
        float acc = 0.f;
        #pragma unroll
        for (int j = 0; j < 4; ++j) {
          uint2  e2 = ep[j];
          float4 u4 = up[j];
          float4 w4 = wp[j];
          float e0, e1, e2f, e3;
          unph(e2.x, e0, e1); unph(e2.y, e2f, e3);
          acc += w4.x * ptanh(e0  + u4.x) + w4.y * ptanh(e1 + u4.y)
               + w4.z * ptanh(e2f + u4.z) + w4.w * ptanh(e3 + u4.w);
        }
        spart[bg][oct * 128 + hh] = acc;
      }
    }
    __syncthreads();
    // S3: softmax over t + y, all 4 batches, wave-redundant (no barrier after)
    float yv[BPB];
    #pragma unroll
    for (int bg = 0; bg < BPB; ++bg) {
      float s0 = spart[bg][lane]       + spart[bg][128 + lane]
               + spart[bg][256 + lane] + spart[bg][384 + lane]
               + spart[bg][512 + lane] + spart[bg][640 + lane]
               + spart[bg][768 + lane] + spart[bg][896 + lane];
      float e0 = __expf(s0);
      float es = e0, ys = e0 * sye[bg][lane];
      if (lane < 36) {
        float s1 = spart[bg][64 + lane]  + spart[bg][192 + lane]
                 + spart[bg][320 + lane] + spart[bg][448 + lane]
                 + spart[bg][576 + lane] + spart[bg][704 + lane]
                 + spart[bg][832 + lane] + spart[bg][960 + lane];
        float e1 = __expf(s1);
        es += e1; ys += e1 * sye[bg][64 + lane];
      }
      es = wsum(es); ys = wsum(ys);
      yv[bg] = ys * rcpf_(es) + fcbv;
    }
    // S6: gates, lane-pair K-split, all 4 batches
    #pragma unroll
    for (int bg = 0; bg < BPB; ++bg) {
      const uint4* hr = (const uint4*)((const u32*)shp[bg] + kh * 32);
      float a0 = 0.f, a1 = 0.f, a2 = 0.f, a3 = 0.f;
      #pragma unroll
      for (int k = 0; k < 8; ++k) {
        uint4 hv = hr[k];
        a0 = dot2h(wpkDh[4*k+0], hv.x, a0);
        a1 = dot2h(wpkDh[4*k+1], hv.y, a1);
        a2 = dot2h(wpkDh[4*k+2], hv.z, a2);
        a3 = dot2h(wpkDh[4*k+3], hv.w, a3);
      }
      float g = (a0 + a1) + (a2 + a3);
      g += __shfl_xor(g, 1, 64);
      if (kh == 0) sg[bg][row2] = g + biasD + wihj * yv[bg];
    }
    __syncthreads();
    // S7: pointwise LSTM (tid<512)
    if (tid < 512) {
      float gi = sigm(sg[quad][hh]);
      float gf = sigm(sg[quad][hh + 128]);
      float gg = tanh_(sg[quad][hh + 256]);
      float go = sigm(sg[quad][hh + 384]);
      float c  = gf * sc[quad][hh] + gi * gg;
      sc[quad][hh] = c;
      float d  = go * tanh_(c);
      sh[quad][hh] = d;
      shp[quad][hh] = f2h(d);
      scp[quad][hh] = f2h(c);
    }
    __syncthreads();
  }

  // ---------- final beta -> ctx -> head ----------
  if (wv < BPB) {                     // wave w computes beta for batch w
    const int bg = wv;
    float s0 = spart[bg][lane]       + spart[bg][128 + lane]
             + spart[bg][256 + lane] + spart[bg][384 + lane]
             + spart[bg][512 + lane] + spart[bg][640 + lane]
             + spart[bg][768 + lane] + spart[bg][896 + lane];
    float e0 = __expf(s0);
    float e1 = 0.f;
    if (lane < 36) {
      float s1 = spart[bg][64 + lane]  + spart[bg][192 + lane]
               + spart[bg][320 + lane] + spart[bg][448 + lane]
               + spart[bg][576 + lane] + spart[bg][704 + lane]
               + spart[bg][832 + lane] + spart[bg][960 + lane];
      e1 = __expf(s1);
    }
    float iv = rcpf_(wsum(e0 + e1));
    sye[bg][lane] = e0 * iv;          // overwrite ye with beta
    if (lane < 36) sye[bg][64 + lane] = e1 * iv;
  }
  __syncthreads();
  if (tid < 512) {
    const u16* xeb = qws + (size_t)(b0 + quad) * QS + hh;
    float cx = 0.f;
    #pragma unroll 4
    for (int t = 0; t < T_; ++t)
      cx += sye[quad][t] * h2f(xeb[t * QROW]);
    su[quad][hh] = cx;                // ctx
  }
  __syncthreads();
  if (tid < BPB * C_) {
    int bg = tid >> 5, cls = tid & 31;
    const float* w = fcfW + (size_t)cls * 256;
    float acc = fcfb[cls];
    #pragma unroll 8
    for (int k = 0; k < 128; ++k)
      acc += w[k] * sh[bg][k] + w[128 + k] * su[bg][k];
    out[(size_t)(b0 + bg) * C_ + cls] = acc;
  }
}

// ================== fallback (R7 structure, no workspace) ==================
__global__ void __launch_bounds__(NTF)
darnn_fb(const float* __restrict__ X,
         const float* __restrict__ eWih, const float* __restrict__ eWhh,
         const float* __restrict__ ebih, const float* __restrict__ ebhh,
         const float* __restrict__ eAw,
         const float* __restrict__ dW1,  const float* __restrict__ db1,
         const float* __restrict__ dW2,
         const float* __restrict__ dWih, const float* __restrict__ dWhh,
         const float* __restrict__ dbih, const float* __restrict__ dbhh,
         const float* __restrict__ fcW,  const float* __restrict__ fcb,
         const float* __restrict__ fcfW, const float* __restrict__ fcfb,
         float* __restrict__ out)
{
  __shared__ __align__(16) u16   sxh[12800];
  __shared__ __align__(16) u16   sXe[12800];
  __shared__ __align__(16) float sg[512];
  __shared__ __align__(16) float sh[128];
  __shared__ __align__(16) float sc[128];
  __shared__ __align__(16) u16   shp[128];
  __shared__ __align__(16) u16   scp[128];
  __shared__ __align__(16) float su[128];
  __shared__ __align__(16) float spart[512];
  __shared__ __align__(16) float sscore[128];
  __shared__ __align__(16) float sctx[128];
  __shared__ float sred[8];
  __shared__ float sredY[2];

  const int tid  = threadIdx.x;
  const int lane = tid & 63;
  const int wv   = tid >> 6;
  const int b    = blockIdx.x;
  const int hh   = tid & 127;
  const int q4   = tid >> 7;

  {
    const float4* Xb4 = (const float4*)(X + (size_t)b * 12800);
    u32* dst = (u32*)sxh;
    #pragma unroll
    for (int i = 0; i < 7; ++i) {
      int idx = tid + NTF * i;
      if (idx < 3200) {
        float4 v = Xb4[idx];
        dst[2*idx]   = pkh2(v.x, v.y);
        dst[2*idx+1] = pkh2(v.z, v.w);
      }
    }
  }
  __syncthreads();
  float sval = 0.f;
  if (tid < 128) {
    #pragma unroll 4
    for (int t = 0; t < T_; ++t)
      sval += h2f(sxh[t * 128 + tid]) * eAw[256 + t];
  }
  float ee = (tid < 128) ? __expf(sval) : 0.f;
  float sm = wsum(ee);
  if (lane == 0 && wv < 2) sred[2 + wv] = sm;
  __syncthreads();
  if (tid < 128) {
    su[tid] = ee * rcpf_(sred[2] + sred[3]);
    sh[tid] = 0.f; sc[tid] = 0.f; shp[tid] = 0; scp[tid] = 0;
  }
  __syncthreads();
  {
    u32* sx32 = (u32*)sxh;
    #pragma unroll
    for (int i = 0; i < 13; ++i) {
      int p = tid + NTF * i;
      if (p < 6400) {
        float lo, hi; unph(sx32[p], lo, hi);
        int m = (2 * p) & 127;
        sx32[p] = pkh2(lo * su[m], hi * su[m + 1]);
      }
    }
  }
  __syncthreads();

  u32 wpkH[64], wpkI[64];
  {
    const float4* wr = (const float4*)(eWhh + (size_t)tid * 128);
    #pragma unroll
    for (int i = 0; i < 32; ++i) {
      float4 v = wr[i];
      wpkH[2*i] = pkh2(v.x, v.y); wpkH[2*i+1] = pkh2(v.z, v.w);
    }
    const float4* wi = (const float4*)(eWih + (size_t)tid * 128);
    #pragma unroll
    for (int i = 0; i < 32; ++i) {
      float4 v = wi[i];
      wpkI[2*i] = pkh2(v.x, v.y); wpkI[2*i+1] = pkh2(v.z, v.w);
    }
  }
  float biasg = ebih[tid] + ebhh[tid];

  for (int t = 0; t < T_; ++t) {
    float a0 = biasg, a1 = 0.f, a2 = 0.f, a3 = 0.f;
    const uint4* hr = (const uint4*)(const u32*)shp;
    #pragma unroll
    for (int k = 0; k < 16; ++k) {
      uint4 hv = hr[k];
      a0 = dot2h(wpkH[4*k+0], hv.x, a0);
      a1 = dot2h(wpkH[4*k+1], hv.y, a1);
      a2 = dot2h(wpkH[4*k+2], hv.z, a2);
      a3 = dot2h(wpkH[4*k+3], hv.w, a3);
    }
    const uint4* xr = (const uint4*)((const u32*)sxh + t * 64);
    #pragma unroll
    for (int k = 0; k < 16; ++k) {
      uint4 xv = xr[k];
      a0 = dot2h(wpkI[4*k+0], xv.x, a0);
      a1 = dot2h(wpkI[4*k+1], xv.y, a1);
      a2 = dot2h(wpkI[4*k+2], xv.z, a2);
      a3 = dot2h(wpkI[4*k+3], xv.w, a3);
    }
    sg[tid] = (a0 + a1) + (a2 + a3);
    __syncthreads();
    if (tid < 128) {
      float gi = sigm(sg[tid]);
      float gf = sigm(sg[tid + 128]);
      float gg = tanh_(sg[tid + 256]);
      float go = sigm(sg[tid + 384]);
      float c  = gf * sc[tid] + gi * gg;
      sc[tid]  = c;
      float h  = go * tanh_(c);
      sh[tid]  = h;
      u16 hb = f2h(h);
      shp[tid] = hb; scp[tid] = f2h(c);
      sXe[t * 128 + tid] = hb;
    }
    __syncthreads();
  }

  {
    u32 wtp[64];
    const float4* w4 = (const float4*)(dW1 + (size_t)hh * 384 + 256);
    #pragma unroll
    for (int i = 0; i < 32; ++i) {
      float4 v = w4[i];
      wtp[2*i] = pkh2(v.x, v.y); wtp[2*i+1] = pkh2(v.z, v.w);
    }
    float b1v = db1[hh];
    u16 e1out[25];
    #pragma unroll 1
    for (int i = 0; i < 25; ++i) {
      int t = q4 * 25 + i;
      const uint4* xe4 = (const uint4*)(sXe + t * 128);
      float a0 = 0.f, a1 = 0.f;
      #pragma unroll
      for (int k = 0; k < 16; ++k) {
        uint4 xv = xe4[k];
        a0 = dot2h(wtp[4*k+0], xv.x, a0);
        a1 = dot2h(wtp[4*k+1], xv.y, a1);
        a0 = dot2h(wtp[4*k+2], xv.z, a0);
        a1 = dot2h(wtp[4*k+3], xv.w, a1);
      }
      e1out[i] = f2h(a0 + a1 + b1v);
    }
    __syncthreads();
    #pragma unroll 1
    for (int i = 0; i < 25; ++i)
      sxh[(q4 * 25 + i) * 128 + hh] = e1out[i];
  }

  u32 wpkD[64];
  {
    const float4* wr = (const float4*)(dWhh + (size_t)tid * 128);
    #pragma unroll
    for (int i = 0; i < 32; ++i) {
      float4 v = wr[i];
      wpkD[2*i] = pkh2(v.x, v.y); wpkD[2*i+1] = pkh2(v.z, v.w);
    }
  }
  u32 wtpU[32];
  {
    const float4* wu = (const float4*)(dW1 + (size_t)hh * 384 + q4 * 64);
    #pragma unroll
    for (int i = 0; i < 16; ++i) {
      float4 v = wu[i];
      wtpU[2*i] = pkh2(v.x, v.y); wtpU[2*i+1] = pkh2(v.z, v.w);
    }
  }
  float biasD = dbih[tid] + dbhh[tid];
  float wihj  = dWih[tid];
  float w2a   = dW2[lane];
  float w2b   = dW2[lane + 64];
  float fcbv  = fcb[0];
  float fcwv  = (tid < 128) ? fcW[tid] : 0.f;
  if (tid < 128) { sh[tid] = 0.f; sc[tid] = 0.f; shp[tid] = 0; scp[tid] = 0; }
  __syncthreads();

  for (int step = 0; step < T_; ++step) {
    {
      const u32* base = (q4 < 2) ? (const u32*)shp : (const u32*)scp;
      const uint4* vp = (const uint4*)(base + (q4 & 1) * 32);
      float a0 = 0.f, a1 = 0.f;
      #pragma unroll
      for (int k = 0; k < 8; ++k) {
        uint4 v = vp[k];
        a0 = dot2h(wtpU[4*k+0], v.x, a0);
        a1 = dot2h(wtpU[4*k+1], v.y, a1);
        a0 = dot2h(wtpU[4*k+2], v.z, a0);
        a1 = dot2h(wtpU[4*k+3], v.w, a1);
      }
      spart[q4 * 128 + hh] = a0 + a1;
    }
    __syncthreads();
    {
      float ul = spart[lane] + spart[128 + lane]
               + spart[256 + lane] + spart[384 + lane];
      float uh = spart[64 + lane] + spart[192 + lane]
               + spart[320 + lane] + spart[448 + lane];
      #pragma unroll 1
      for (int i = 0; i < 13; ++i) {
        int t = wv + 8 * i;
        if (t < T_) {
          float v = w2a * ptanh(h2f(sxh[t * 128 + lane]) + ul)
                  + w2b * ptanh(h2f(sxh[t * 128 + 64 + lane]) + uh);
          v = wsum(v);
          if (lane == 0) sscore[t] = v;
        }
      }
    }
    __syncthreads();
    if (wv == 0) {
      float s0 = sscore[lane];
      float E0 = __expf(s0);
      float E1v = (lane < 36) ? __expf(sscore[lane + 64]) : 0.f;
      float s  = wsum(E0 + E1v);
      float iv = rcpf_(s);
      sscore[lane] = E0 * iv;
      if (lane < 36) sscore[lane + 64] = E1v * iv;
    }
    __syncthreads();
    {
      float pc = 0.f;
      #pragma unroll
      for (int i = 0; i < 25; ++i) {
        int t = q4 * 25 + i;
        pc += sscore[t] * h2f(sXe[t * 128 + hh]);
      }
      spart[q4 * 128 + hh] = pc;
    }
    __syncthreads();
    {
      float v = 0.f;
      if (tid < 128) {
        float cx = spart[tid] + spart[tid + 128]
                 + spart[tid + 256] + spart[tid + 384];
        sctx[tid] = cx;
        v = fcwv * cx;
      }
      v = wsum(v);
      if (lane == 0 && wv < 2) sredY[wv] = v;
    }
    __syncthreads();
    {
      float yt = sredY[0] + sredY[1] + fcbv;
      float a0 = biasD + wihj * yt, a1 = 0.f, a2 = 0.f, a3 = 0.f;
      const uint4* hr = (const uint4*)(const u32*)shp;
      #pragma unroll
      for (int k = 0; k < 16; ++k) {
        uint4 hv = hr[k];
        a0 = dot2h(wpkD[4*k+0], hv.x, a0);
        a1 = dot2h(wpkD[4*k+1], hv.y, a1);
        a2 = dot2h(wpkD[4*k+2], hv.z, a2);
        a3 = dot2h(wpkD[4*k+3], hv.w, a3);
      }
      sg[tid] = (a0 + a1) + (a2 + a3);
    }
    __syncthreads();
    if (tid < 128) {
      float gi = sigm(sg[tid]);
      float gf = sigm(sg[tid + 128]);
      float gg = tanh_(sg[tid + 256]);
      float go = sigm(sg[tid + 384]);
      float c  = gf * sc[tid] + gi * gg;
      sc[tid]  = c;
      float d  = go * tanh_(c);
      sh[tid]  = d;
      shp[tid] = f2h(d);
      scp[tid] = f2h(c);
    }
    __syncthreads();
  }

  if (tid < C_) {
    float acc = fcfb[tid];
    const float* w = fcfW + (size_t)tid * 256;
    #pragma unroll 8
    for (int k = 0; k < 128; ++k)
      acc += w[k] * sh[k] + w[128 + k] * sctx[k];
    out[(size_t)b * C_ + tid] = acc;
  }
}

extern "C" void kernel_launch(void* const* d_in, const int* in_sizes, int n_in,
                              void* d_out, int out_size, void* d_ws, size_t ws_size,
                              hipStream_t stream) {
  (void)n_in; (void)out_size;
  const float* X    = (const float*)d_in[0];
  const float* eWih = (const float*)d_in[1];
  const float* eWhh = (const float*)d_in[2];
  const float* ebih = (const float*)d_in[3];
  const float* ebhh = (const float*)d_in[4];
  const float* eAw  = (const float*)d_in[5];
  const float* eAb  = (const float*)d_in[6];
  const float* dW1  = (const float*)d_in[7];
  const float* db1  = (const float*)d_in[8];
  const float* dW2  = (const float*)d_in[9];
  const float* db2  = (const float*)d_in[10];
  const float* dWih = (const float*)d_in[11];
  const float* dWhh = (const float*)d_in[12];
  const float* dbih = (const float*)d_in[13];
  const float* dbhh = (const float*)d_in[14];
  const float* fcW  = (const float*)d_in[15];
  const float* fcb  = (const float*)d_in[16];
  const float* fcfW = (const float*)d_in[17];
  const float* fcfb = (const float*)d_in[18];
  float* out = (float*)d_out;

  const int B = in_sizes[0] / (T_ * 128);
  const size_t needQ = (size_t)B * QS * sizeof(u16);
  if (ws_size >= needQ && (B % BPB) == 0) {
    darnn4<<<dim3(B / BPB), dim3(NT), 0, stream>>>(
        X, eWih, eWhh, ebih, ebhh, eAw, eAb,
        dW1, db1, dW2, db2, dWih, dWhh, dbih, dbhh,
        fcW, fcb, fcfW, fcfb, (u16*)d_ws, out);
  } else {
    darnn_fb<<<dim3(B), dim3(NTF), 0, stream>>>(
        X, eWih, eWhh, ebih, ebhh, eAw,
        dW1, db1, dW2, dWih, dWhh, dbih, dbhh,
        fcW, fcb, fcfW, fcfb, out);
  }
}

// Round 5
// 1701.760 us; speedup vs baseline: 1.0960x; 1.0960x over previous
//
#include <hip/hip_runtime.h>

// DA-RNN fused — R13: R12 + bank-conflict-free interleaved K-split.
//  * R12 post-mortem: lane-pair split with CONTIGUOUS halves (kh*64) put the
//    two halves exactly 128 B apart -> same 4 LDS banks -> 32-way aliasing;
//    SQ_LDS_BANK_CONFLICT 3.7M -> 104.9M, 1865 us.
//  * R13: chunk-INTERLEAVED split: thread kh reads chunks {2k+kh} (16 B gate
//    chunks / 8 B Q chunks). Per instruction the wave reads one contiguous
//    32 B (16 B) region: even lanes banks 8k..+3, odd lanes 8k+4..+7 ->
//    disjoint banks, conflict-free, same instruction count. Weight regs
//    loaded to match interleaved h-coverage; shfl_xor(1) combine unchanged.
//  * Everything else = R12: 1024-thr block, BPB=4, grid 256, 64-VGPR live set.

typedef unsigned int   u32;
typedef unsigned short u16;

#define T_   100
#define C_   32
#define NT   1024
#define NTF  512
#define BPB  4
#define TS   132
#define QROW 512
#define QS   (T_ * QROW)

typedef __attribute__((ext_vector_type(2))) __fp16 h16x2;

#if __has_builtin(__builtin_amdgcn_fdot2)
#define HAVE_FDOT2 1
#else
#define HAVE_FDOT2 0
#endif

__device__ __forceinline__ u32 pkh2(float a, float b) {
#if __has_builtin(__builtin_amdgcn_cvt_pkrtz)
  h16x2 p = __builtin_amdgcn_cvt_pkrtz(a, b);
  return __builtin_bit_cast(u32, p);
#else
  union { __fp16 h[2]; u32 u; } v;
  v.h[0] = (__fp16)a; v.h[1] = (__fp16)b;
  return v.u;
#endif
}
__device__ __forceinline__ void unph(u32 p, float& lo, float& hi) {
  union { u32 u; __fp16 h[2]; } v; v.u = p;
  lo = (float)v.h[0]; hi = (float)v.h[1];
}
__device__ __forceinline__ u16 f2h(float f) {
  union { __fp16 h; u16 u; } v; v.h = (__fp16)f; return v.u;
}
__device__ __forceinline__ float h2f(u16 u) {
  union { u16 u; __fp16 h; } v; v.u = u; return (float)v.h;
}
__device__ __forceinline__ float dot2h(u32 w, u32 x, float acc) {
#if HAVE_FDOT2
  return __builtin_amdgcn_fdot2(__builtin_bit_cast(h16x2, w),
                                __builtin_bit_cast(h16x2, x),
                                acc, false);
#else
  float a, b, c, d;
  unph(w, a, b); unph(x, c, d);
  return fmaf(a, c, fmaf(b, d, acc));
#endif
}

#if __has_builtin(__builtin_amdgcn_rcpf)
__device__ __forceinline__ float rcpf_(float x){ return __builtin_amdgcn_rcpf(x); }
#else
__device__ __forceinline__ float rcpf_(float x){ return 1.0f / x; }
#endif
__device__ __forceinline__ float sigm(float x){ return rcpf_(1.0f + __expf(-x)); }
__device__ __forceinline__ float tanh_(float x){
  return 1.0f - 2.0f * rcpf_(1.0f + __expf(2.0f * x));
}
__device__ __forceinline__ float ptanh(float x){
  x = fminf(1.0f, fmaxf(-1.0f, x));
  float x2 = x * x;
  float p  = fmaf(x2, 0.1333333f, -0.3333333f);
  return x * fmaf(x2, p, 1.0f);
}
__device__ __forceinline__ float wsum(float v){
  #pragma unroll
  for (int o = 32; o; o >>= 1) v += __shfl_xor(v, o, 64);
  return v;
}

// ==================== fast kernel (4 batches, 1024 threads) =================
__global__ void __launch_bounds__(NT)
darnn4(const float* __restrict__ X,
       const float* __restrict__ eWih, const float* __restrict__ eWhh,
       const float* __restrict__ ebih, const float* __restrict__ ebhh,
       const float* __restrict__ eAw,  const float* __restrict__ eAb,
       const float* __restrict__ dW1,  const float* __restrict__ db1,
       const float* __restrict__ dW2,  const float* __restrict__ db2,
       const float* __restrict__ dWih, const float* __restrict__ dWhh,
       const float* __restrict__ dbih, const float* __restrict__ dbhh,
       const float* __restrict__ fcW,  const float* __restrict__ fcb,
       const float* __restrict__ fcfW, const float* __restrict__ fcfb,
       u16* __restrict__ qws,
       float* __restrict__ out)
{
  // LDS ~137.7 KB, one block/CU
  __shared__ __align__(16) u16   sE1[BPB][T_ * TS];   // 105600
  __shared__ __align__(16) float sg[BPB][512];        //   8192
  __shared__ __align__(16) float sh[BPB][128];        //   2048
  __shared__ __align__(16) float sc[BPB][128];        //   2048
  __shared__ __align__(16) u16   shp[BPB][128];       //   1024
  __shared__ __align__(16) u16   scp[BPB][128];       //   1024
  __shared__ __align__(16) float su[BPB][128];        //   2048
  __shared__ __align__(16) float spart[BPB][1024];    //  16384
  __shared__ __align__(16) float sye[BPB][128];       //   2048
  __shared__ __align__(16) float sw2[128];            //    512
  __shared__ float sred[16];

  const int tid  = threadIdx.x;
  const int lane = tid & 63;
  const int wv   = tid >> 6;     // 0..15
  const int hh   = tid & 127;
  const int oct  = tid >> 7;     // 0..7 (column-eighth)
  const int quad = oct & 3;      // batch idx on tid<512 paths
  const int kh   = tid & 1;      // K-half for lane-pair split
  const int row2 = tid >> 1;     // 0..511 gate row / slot
  const int b0   = blockIdx.x * BPB;

  (void)eAb; (void)db2;          // cancel under softmax shift-invariance

  if (tid < 128) sw2[tid] = dW2[tid];

  // ---------- alpha (h/c terms cancel) + x_tilde (tid<512) ----------
  {
    const float* xp = X + (size_t)(b0 + quad) * 12800 + hh;
    if (tid < 512) {
      float sval = 0.f;
      #pragma unroll 4
      for (int t = 0; t < T_; ++t) sval += xp[t * 128] * eAw[256 + t];
      float e = __expf(sval);
      float s = wsum(e);
      if (lane == 0) sred[wv] = s;
      spart[quad][hh] = e;               // stash e across the barrier
    }
    __syncthreads();
    if (tid < 512) {
      float e  = spart[quad][hh];
      float al = e * rcpf_(sred[quad * 2] + sred[quad * 2 + 1]);
      #pragma unroll 4
      for (int t = 0; t < T_; ++t)
        sE1[quad][t * TS + hh] = f2h(al * xp[t * 128]);
      sh[quad][hh] = 0.f; sc[quad][hh] = 0.f;
      shp[quad][hh] = 0;  scp[quad][hh] = 0;
    }
  }
  __syncthreads();

  // ---- Q GEMM: Q[b][t][r] = eWih[r,:]·x_tilde (interleaved K-split) ----
  // chunk c = 2k+kh covers x-cols [4c, 4c+4); per-instr wave reads contiguous
  // 16 B (even lanes first 8 B, odd next 8 B) -> disjoint banks.
  {
    u32 wqh[32];
    #pragma unroll
    for (int k = 0; k < 16; ++k) {
      float4 v = *(const float4*)(eWih + (size_t)row2 * 128 + (2*k + kh) * 4);
      wqh[2*k]   = pkh2(v.x, v.y);
      wqh[2*k+1] = pkh2(v.z, v.w);
    }
    #pragma unroll 1
    for (int bg = 0; bg < BPB; ++bg) {
      u16* qb = qws + (size_t)(b0 + bg) * QS;
      #pragma unroll 1
      for (int t = 0; t < T_; ++t) {
        const u32* xr = (const u32*)(&sE1[bg][t * TS]);
        float a0 = 0.f, a1 = 0.f;
        #pragma unroll
        for (int k = 0; k < 16; ++k) {
          uint2 xv = *(const uint2*)(xr + 4*k + 2*kh);
          a0 = dot2h(wqh[2*k],   xv.x, a0);
          a1 = dot2h(wqh[2*k+1], xv.y, a1);
        }
        float g = a0 + a1;
        g += __shfl_xor(g, 1, 64);
        if (kh == 0) qb[t * QROW + row2] = f2h(g);
      }
    }
  }
  __syncthreads();   // Q visible to all

  // ---------- encoder (2 barriers/step; interleaved K-split, 4 bg) --------
  // chunk c = 2k+kh covers h-cols [8c, 8c+8); per-instr wave reads contiguous
  // 32 B (even lanes banks 8k..+3, odd 8k+4..+7) -> conflict-free.
  {
    u32 wpkHh[32];
    #pragma unroll
    for (int k = 0; k < 8; ++k) {
      const float4* wr = (const float4*)(eWhh + (size_t)row2 * 128 + (2*k + kh) * 8);
      float4 v0 = wr[0], v1 = wr[1];
      wpkHh[4*k+0] = pkh2(v0.x, v0.y);
      wpkHh[4*k+1] = pkh2(v0.z, v0.w);
      wpkHh[4*k+2] = pkh2(v1.x, v1.y);
      wpkHh[4*k+3] = pkh2(v1.z, v1.w);
    }
    float biasg = ebih[row2] + ebhh[row2];

    u16 qc[BPB];
    #pragma unroll
    for (int bg = 0; bg < BPB; ++bg)
      qc[bg] = qws[(size_t)(b0 + bg) * QS + row2];

    for (int t = 0; t < T_; ++t) {
      u16 qn[BPB];
      #pragma unroll
      for (int bg = 0; bg < BPB; ++bg)
        qn[bg] = (t + 1 < T_)
               ? qws[(size_t)(b0 + bg) * QS + (t + 1) * QROW + row2]
               : (u16)0;
      #pragma unroll
      for (int bg = 0; bg < BPB; ++bg) {
        const u32* hb = (const u32*)shp[bg];
        float a0 = 0.f, a1 = 0.f, a2 = 0.f, a3 = 0.f;
        #pragma unroll
        for (int k = 0; k < 8; ++k) {
          uint4 hv = *(const uint4*)(hb + 8*k + 4*kh);
          a0 = dot2h(wpkHh[4*k+0], hv.x, a0);
          a1 = dot2h(wpkHh[4*k+1], hv.y, a1);
          a2 = dot2h(wpkHh[4*k+2], hv.z, a2);
          a3 = dot2h(wpkHh[4*k+3], hv.w, a3);
        }
        float g = (a0 + a1) + (a2 + a3);
        g += __shfl_xor(g, 1, 64);
        if (kh == 0) sg[bg][row2] = g + biasg + h2f(qc[bg]);
      }
      __syncthreads();
      if (tid < 512) {
        float gi = sigm(sg[quad][hh]);
        float gf = sigm(sg[quad][hh + 128]);
        float gg = tanh_(sg[quad][hh + 256]);
        float go = sigm(sg[quad][hh + 384]);
        float c  = gf * sc[quad][hh] + gi * gg;
        sc[quad][hh] = c;
        float h  = go * tanh_(c);
        sh[quad][hh] = h;
        u16 hb = f2h(h);
        shp[quad][hh] = hb;
        scp[quad][hh] = f2h(c);
        // Xe row t shares Q's slab (Q[t] already consumed; barrier-ordered)
        qws[(size_t)(b0 + quad) * QS + t * QROW + hh] = hb;
      }
      __syncthreads();
      #pragma unroll
      for (int bg = 0; bg < BPB; ++bg) qc[bg] = qn[bg];
    }
  }

  // ---------- ye[t] = fcW · Xe[t]  (oct-split partials) ----------
  if (hh < T_) {
    #pragma unroll 1
    for (int bg = 0; bg < BPB; ++bg) {
      const uint2* xe = (const uint2*)(qws + (size_t)(b0 + bg) * QS
                                       + hh * QROW + oct * 16);
      const float* fw = fcW + oct * 16;
      float a = 0.f;
      #pragma unroll
      for (int k = 0; k < 4; ++k) {
        uint2 xv = xe[k];
        float l0, l1, l2, l3;
        unph(xv.x, l0, l1); unph(xv.y, l2, l3);
        a += fw[4*k]*l0 + fw[4*k+1]*l1 + fw[4*k+2]*l2 + fw[4*k+3]*l3;
      }
      spart[bg][oct * 128 + hh] = a;
    }
  }
  __syncthreads();
  if (tid < 512 && hh < T_) {
    float a = spart[quad][hh]       + spart[quad][128 + hh]
            + spart[quad][256 + hh] + spart[quad][384 + hh]
            + spart[quad][512 + hh] + spart[quad][640 + hh]
            + spart[quad][768 + hh] + spart[quad][896 + hh];
    sye[quad][hh] = a;
  }
  __syncthreads();

  // ---- E1[t][h] = dW1[h][256:384]·Xe[t] + db1[h] (lane-pair K-split) ----
  // (reads GLOBAL qws, wave-uniform address -> no LDS banks involved)
  {
    const int tg = row2 >> 7;        // 0..3 (25-t chunk)
    const int h  = row2 & 127;
    u32 wtph[32];   // dW1[h][256 + kh*64 .. +64)
    const float4* w4p = (const float4*)(dW1 + (size_t)h * 384 + 256 + kh * 64);
    #pragma unroll
    for (int i = 0; i < 16; ++i) {
      float4 v = w4p[i];
      wtph[2*i]   = pkh2(v.x, v.y);
      wtph[2*i+1] = pkh2(v.z, v.w);
    }
    float b1v = db1[h];
    #pragma unroll 1
    for (int bg = 0; bg < BPB; ++bg) {
      const u16* xb = qws + (size_t)(b0 + bg) * QS;
      #pragma unroll 1
      for (int i = 0; i < 25; ++i) {
        const int t = tg * 25 + i;
        const uint2* xe = (const uint2*)(xb + t * QROW + kh * 64);
        float a0 = 0.f, a1 = 0.f;
        #pragma unroll
        for (int k = 0; k < 16; ++k) {
          uint2 xv = xe[k];
          a0 = dot2h(wtph[2*k],   xv.x, a0);
          a1 = dot2h(wtph[2*k+1], xv.y, a1);
        }
        float g = a0 + a1;
        g += __shfl_xor(g, 1, 64);
        if (kh == 0) sE1[bg][t * TS + h] = f2h(g + b1v);
      }
    }
  }

  // ---------- decoder weights (interleaved halves) ----------
  u32 wpkDh[32];   // dWhh[row2], chunks {2k+kh}
  {
    #pragma unroll
    for (int k = 0; k < 8; ++k) {
      const float4* wr = (const float4*)(dWhh + (size_t)row2 * 128 + (2*k + kh) * 8);
      float4 v0 = wr[0], v1 = wr[1];
      wpkDh[4*k+0] = pkh2(v0.x, v0.y);
      wpkDh[4*k+1] = pkh2(v0.z, v0.w);
      wpkDh[4*k+2] = pkh2(v1.x, v1.y);
      wpkDh[4*k+3] = pkh2(v1.z, v1.w);
    }
  }
  u32 wtpU[16];   // dW1 row hh, z-cols [oct*32, oct*32+32)
  {
    const float4* wu = (const float4*)(dW1 + (size_t)hh * 384 + oct * 32);
    #pragma unroll
    for (int i = 0; i < 8; ++i) {
      float4 v = wu[i];
      wtpU[2*i]   = pkh2(v.x, v.y);
      wtpU[2*i+1] = pkh2(v.z, v.w);
    }
  }
  float biasD = dbih[row2] + dbhh[row2];
  float wihj  = dWih[row2];
  float fcbv  = fcb[0];
  if (tid < 512) {
    sh[quad][hh] = 0.f; sc[quad][hh] = 0.f;
    shp[quad][hh] = 0;  scp[quad][hh] = 0;
  }
  __syncthreads();

  // ---------- decoder (5 barriers/step) ----------
  for (int step = 0; step < T_; ++step) {
    // S0: u partials over z=[d;c] cols oct*32..+32, all batches
    // (oct is wave-uniform -> pure broadcast reads)
    #pragma unroll 1
    for (int bg = 0; bg < BPB; ++bg) {
      const u32* bs = (oct < 4) ? (const u32*)shp[bg] + oct * 16
                                : (const u32*)scp[bg] + (oct - 4) * 16;
      const uint4* vp = (const uint4*)bs;
      float a0 = 0.f, a1 = 0.f;
      #pragma unroll
      for (int k = 0; k < 4; ++k) {
        uint4 v = vp[k];
        a0 = dot2h(wtpU[4*k+0], v.x, a0);
        a1 = dot2h(wtpU[4*k+1], v.y, a1);
        a0 = dot2h(wtpU[4*k+2], v.z, a0);
        a1 = dot2h(wtpU[4*k+3], v.w, a1);
      }
      spart[bg][oct * 128 + hh] = a0 + a1;
    }
    __syncthreads();
    // S1: reduce u (tid<512)
    if (tid < 512) {
      float a = spart[quad][hh]       + spart[quad][128 + hh]
              + spart[quad][256 + hh] + spart[quad][384 + hh]
              + spart[quad][512 + hh] + spart[quad][640 + hh]
              + spart[quad][768 + hh] + spart[quad][896 + hh];
      su[quad][hh] = a;
    }
    __syncthreads();
    // S2: score partials: thread (t=hh<100, oct), 16 h each
    if (hh < T_) {
      #pragma unroll 1
      for (int bg = 0; bg < BPB; ++bg) {
        const uint2*  ep = (const uint2*)(&sE1[bg][hh * TS + oct * 16]);
        const float4* up = (const float4*)(&su[bg][oct * 16]);
        const float4* wp = (const float4*)(&sw2[oct * 16]);
        float acc = 0.f;
        #pragma unroll
        for (int j = 0; j < 4; ++j) {
          uint2  e2 = ep[j];
          float4 u4 = up[j];
          float4 w4 = wp[j];
          float e0, e1, e2f, e3;
          unph(e2.x, e0, e1); unph(e2.y, e2f, e3);
          acc += w4.x * ptanh(e0  + u4.x) + w4.y * ptanh(e1 + u4.y)
               + w4.z * ptanh(e2f + u4.z) + w4.w * ptanh(e3 + u4.w);
        }
        spart[bg][oct * 128 + hh] = acc;
      }
    }
    __syncthreads();
    // S3: softmax over t + y, all 4 batches, wave-redundant (no barrier after)
    float yv[BPB];
    #pragma unroll
    for (int bg = 0; bg < BPB; ++bg) {
      float s0 = spart[bg][lane]       + spart[bg][128 + lane]
               + spart[bg][256 + lane] + spart[bg][384 + lane]
               + spart[bg][512 + lane] + spart[bg][640 + lane]
               + spart[bg][768 + lane] + spart[bg][896 + lane];
      float e0 = __expf(s0);
      float es = e0, ys = e0 * sye[bg][lane];
      if (lane < 36) {
        float s1 = spart[bg][64 + lane]  + spart[bg][192 + lane]
                 + spart[bg][320 + lane] + spart[bg][448 + lane]
                 + spart[bg][576 + lane] + spart[bg][704 + lane]
                 + spart[bg][832 + lane] + spart[bg][960 + lane];
        float e1 = __expf(s1);
        es += e1; ys += e1 * sye[bg][64 + lane];
      }
      es = wsum(es); ys = wsum(ys);
      yv[bg] = ys * rcpf_(es) + fcbv;
    }
    // S6: gates, interleaved K-split, all 4 batches
    #pragma unroll
    for (int bg = 0; bg < BPB; ++bg) {
      const u32* hb = (const u32*)shp[bg];
      float a0 = 0.f, a1 = 0.f, a2 = 0.f, a3 = 0.f;
      #pragma unroll
      for (int k = 0; k < 8; ++k) {
        uint4 hv = *(const uint4*)(hb + 8*k + 4*kh);
        a0 = dot2h(wpkDh[4*k+0], hv.x, a0);
        a1 = dot2h(wpkDh[4*k+1], hv.y, a1);
        a2 = dot2h(wpkDh[4*k+2], hv.z, a2);
        a3 = dot2h(wpkDh[4*k+3], hv.w, a3);
      }
      float g = (a0 + a1) + (a2 + a3);
      g += __shfl_xor(g, 1, 64);
      if (kh == 0) sg[bg][row2] = g + biasD + wihj * yv[bg];
    }
    __syncthreads();
    // S7: pointwise LSTM (tid<512)
    if (tid < 512) {
      float gi = sigm(sg[quad][hh]);
      float gf = sigm(sg[quad][hh + 128]);
      float gg = tanh_(sg[quad][hh + 256]);
      float go = sigm(sg[quad][hh + 384]);
      float c  = gf * sc[quad][hh] + gi * gg;
      sc[quad][hh] = c;
      float d  = go * tanh_(c);
      sh[quad][hh] = d;
      shp[quad][hh] = f2h(d);
      scp[quad][hh] = f2h(c);
    }
    __syncthreads();
  }

  // ---------- final beta -> ctx -> head ----------
  if (wv < BPB) {                     // wave w computes beta for batch w
    const int bg = wv;
    float s0 = spart[bg][lane]       + spart[bg][128 + lane]
             + spart[bg][256 + lane] + spart[bg][384 + lane]
             + spart[bg][512 + lane] + spart[bg][640 + lane]
             + spart[bg][768 + lane] + spart[bg][896 + lane];
    float e0 = __expf(s0);
    float e1 = 0.f;
    if (lane < 36) {
      float s1 = spart[bg][64 + lane]  + spart[bg][192 + lane]
               + spart[bg][320 + lane] + spart[bg][448 + lane]
               + spart[bg][576 + lane] + spart[bg][704 + lane]
               + spart[bg][832 + lane] + spart[bg][960 + lane];
      e1 = __expf(s1);
    }
    float iv = rcpf_(wsum(e0 + e1));
    sye[bg][lane] = e0 * iv;          // overwrite ye with beta
    if (lane < 36) sye[bg][64 + lane] = e1 * iv;
  }
  __syncthreads();
  if (tid < 512) {
    const u16* xeb = qws + (size_t)(b0 + quad) * QS + hh;
    float cx = 0.f;
    #pragma unroll 4
    for (int t = 0; t < T_; ++t)
      cx += sye[quad][t] * h2f(xeb[t * QROW]);
    su[quad][hh] = cx;                // ctx
  }
  __syncthreads();
  if (tid < BPB * C_) {
    int bg = tid >> 5, cls = tid & 31;
    const float* w = fcfW + (size_t)cls * 256;
    float acc = fcfb[cls];
    #pragma unroll 8
    for (int k = 0; k < 128; ++k)
      acc += w[k] * sh[bg][k] + w[128 + k] * su[bg][k];
    out[(size_t)(b0 + bg) * C_ + cls] = acc;
  }
}

// ================== fallback (R7 structure, no workspace) ==================
__global__ void __launch_bounds__(NTF)
darnn_fb(const float* __restrict__ X,
         const float* __restrict__ eWih, const float* __restrict__ eWhh,
         const float* __restrict__ ebih, const float* __restrict__ ebhh,
         const float* __restrict__ eAw,
         const float* __restrict__ dW1,  const float* __restrict__ db1,
         const float* __restrict__ dW2,
         const float* __restrict__ dWih, const float* __restrict__ dWhh,
         const float* __restrict__ dbih, const float* __restrict__ dbhh,
         const float* __restrict__ fcW,  const float* __restrict__ fcb,
         const float* __restrict__ fcfW, const float* __restrict__ fcfb,
         float* __restrict__ out)
{
  __shared__ __align__(16) u16   sxh[12800];
  __shared__ __align__(16) u16   sXe[12800];
  __shared__ __align__(16) float sg[512];
  __shared__ __align__(16) float sh[128];
  __shared__ __align__(16) float sc[128];
  __shared__ __align__(16) u16   shp[128];
  __shared__ __align__(16) u16   scp[128];
  __shared__ __align__(16) float su[128];
  __shared__ __align__(16) float spart[512];
  __shared__ __align__(16) float sscore[128];
  __shared__ __align__(16) float sctx[128];
  __shared__ float sred[8];
  __shared__ float sredY[2];

  const int tid  = threadIdx.x;
  const int lane = tid & 63;
  const int wv   = tid >> 6;
  const int b    = blockIdx.x;
  const int hh   = tid & 127;
  const int q4   = tid >> 7;

  {
    const float4* Xb4 = (const float4*)(X + (size_t)b * 12800);
    u32* dst = (u32*)sxh;
    #pragma unroll
    for (int i = 0; i < 7; ++i) {
      int idx = tid + NTF * i;
      if (idx < 3200) {
        float4 v = Xb4[idx];
        dst[2*idx]   = pkh2(v.x, v.y);
        dst[2*idx+1] = pkh2(v.z, v.w);
      }
    }
  }
  __syncthreads();
  float sval = 0.f;
  if (tid < 128) {
    #pragma unroll 4
    for (int t = 0; t < T_; ++t)
      sval += h2f(sxh[t * 128 + tid]) * eAw[256 + t];
  }
  float ee = (tid < 128) ? __expf(sval) : 0.f;
  float sm = wsum(ee);
  if (lane == 0 && wv < 2) sred[2 + wv] = sm;
  __syncthreads();
  if (tid < 128) {
    su[tid] = ee * rcpf_(sred[2] + sred[3]);
    sh[tid] = 0.f; sc[tid] = 0.f; shp[tid] = 0; scp[tid] = 0;
  }
  __syncthreads();
  {
    u32* sx32 = (u32*)sxh;
    #pragma unroll
    for (int i = 0; i < 13; ++i) {
      int p = tid + NTF * i;
      if (p < 6400) {
        float lo, hi; unph(sx32[p], lo, hi);
        int m = (2 * p) & 127;
        sx32[p] = pkh2(lo * su[m], hi * su[m + 1]);
      }
    }
  }
  __syncthreads();

  u32 wpkH[64], wpkI[64];
  {
    const float4* wr = (const float4*)(eWhh + (size_t)tid * 128);
    #pragma unroll
    for (int i = 0; i < 32; ++i) {
      float4 v = wr[i];
      wpkH[2*i] = pkh2(v.x, v.y); wpkH[2*i+1] = pkh2(v.z, v.w);
    }
    const float4* wi = (const float4*)(eWih + (size_t)tid * 128);
    #pragma unroll
    for (int i = 0; i < 32; ++i) {
      float4 v = wi[i];
      wpkI[2*i] = pkh2(v.x, v.y); wpkI[2*i+1] = pkh2(v.z, v.w);
    }
  }
  float biasg = ebih[tid] + ebhh[tid];

  for (int t = 0; t < T_; ++t) {
    float a0 = biasg, a1 = 0.f, a2 = 0.f, a3 = 0.f;
    const uint4* hr = (const uint4*)(const u32*)shp;
    #pragma unroll
    for (int k = 0; k < 16; ++k) {
      uint4 hv = hr[k];
      a0 = dot2h(wpkH[4*k+0], hv.x, a0);
      a1 = dot2h(wpkH[4*k+1], hv.y, a1);
      a2 = dot2h(wpkH[4*k+2], hv.z, a2);
      a3 = dot2h(wpkH[4*k+3], hv.w, a3);
    }
    const uint4* xr = (const uint4*)((const u32*)sxh + t * 64);
    #pragma unroll
    for (int k = 0; k < 16; ++k) {
      uint4 xv = xr[k];
      a0 = dot2h(wpkI[4*k+0], xv.x, a0);
      a1 = dot2h(wpkI[4*k+1], xv.y, a1);
      a2 = dot2h(wpkI[4*k+2], xv.z, a2);
      a3 = dot2h(wpkI[4*k+3], xv.w, a3);
    }
    sg[tid] = (a0 + a1) + (a2 + a3);
    __syncthreads();
    if (tid < 128) {
      float gi = sigm(sg[tid]);
      float gf = sigm(sg[tid + 128]);
      float gg = tanh_(sg[tid + 256]);
      float go = sigm(sg[tid + 384]);
      float c  = gf * sc[tid] + gi * gg;
      sc[tid]  = c;
      float h  = go * tanh_(c);
      sh[tid]  = h;
      u16 hb = f2h(h);
      shp[tid] = hb; scp[tid] = f2h(c);
      sXe[t * 128 + tid] = hb;
    }
    __syncthreads();
  }

  {
    u32 wtp[64];
    const float4* w4 = (const float4*)(dW1 + (size_t)hh * 384 + 256);
    #pragma unroll
    for (int i = 0; i < 32; ++i) {
      float4 v = w4[i];
      wtp[2*i] = pkh2(v.x, v.y); wtp[2*i+1] = pkh2(v.z, v.w);
    }
    float b1v = db1[hh];
    u16 e1out[25];
    #pragma unroll 1
    for (int i = 0; i < 25; ++i) {
      int t = q4 * 25 + i;
      const uint4* xe4 = (const uint4*)(sXe + t * 128);
      float a0 = 0.f, a1 = 0.f;
      #pragma unroll
      for (int k = 0; k < 16; ++k) {
        uint4 xv = xe4[k];
        a0 = dot2h(wtp[4*k+0], xv.x, a0);
        a1 = dot2h(wtp[4*k+1], xv.y, a1);
        a0 = dot2h(wtp[4*k+2], xv.z, a0);
        a1 = dot2h(wtp[4*k+3], xv.w, a1);
      }
      e1out[i] = f2h(a0 + a1 + b1v);
    }
    __syncthreads();
    #pragma unroll 1
    for (int i = 0; i < 25; ++i)
      sxh[(q4 * 25 + i) * 128 + hh] = e1out[i];
  }

  u32 wpkD[64];
  {
    const float4* wr = (const float4*)(dWhh + (size_t)tid * 128);
    #pragma unroll
    for (int i = 0; i < 32; ++i) {
      float4 v = wr[i];
      wpkD[2*i] = pkh2(v.x, v.y); wpkD[2*i+1] = pkh2(v.z, v.w);
    }
  }
  u32 wtpU[32];
  {
    const float4* wu = (const float4*)(dW1 + (size_t)hh * 384 + q4 * 64);
    #pragma unroll
    for (int i = 0; i < 16; ++i) {
      float4 v = wu[i];
      wtpU[2*i] = pkh2(v.x, v.y); wtpU[2*i+1] = pkh2(v.z, v.w);
    }
  }
  float biasD = dbih[tid] + dbhh[tid];
  float wihj  = dWih[tid];
  float w2a   = dW2[lane];
  float w2b   = dW2[lane + 64];
  float fcbv  = fcb[0];
  float fcwv  = (tid < 128) ? fcW[tid] : 0.f;
  if (tid < 128) { sh[tid] = 0.f; sc[tid] = 0.f; shp[tid] = 0; scp[tid] = 0; }
  __syncthreads();

  for (int step = 0; step < T_; ++step) {
    {
      const u32* base = (q4 < 2) ? (const u32*)shp : (const u32*)scp;
      const uint4* vp = (const uint4*)(base + (q4 & 1) * 32);
      float a0 = 0.f, a1 = 0.f;
      #pragma unroll
      for (int k = 0; k < 8; ++k) {
        uint4 v = vp[k];
        a0 = dot2h(wtpU[4*k+0], v.x, a0);
        a1 = dot2h(wtpU[4*k+1], v.y, a1);
        a0 = dot2h(wtpU[4*k+2], v.z, a0);
        a1 = dot2h(wtpU[4*k+3], v.w, a1);
      }
      spart[q4 * 128 + hh] = a0 + a1;
    }
    __syncthreads();
    {
      float ul = spart[lane] + spart[128 + lane]
               + spart[256 + lane] + spart[384 + lane];
      float uh = spart[64 + lane] + spart[192 + lane]
               + spart[320 + lane] + spart[448 + lane];
      #pragma unroll 1
      for (int i = 0; i < 13; ++i) {
        int t = wv + 8 * i;
        if (t < T_) {
          float v = w2a * ptanh(h2f(sxh[t * 128 + lane]) + ul)
                  + w2b * ptanh(h2f(sxh[t * 128 + 64 + lane]) + uh);
          v = wsum(v);
          if (lane == 0) sscore[t] = v;
        }
      }
    }
    __syncthreads();
    if (wv == 0) {
      float s0 = sscore[lane];
      float E0 = __expf(s0);
      float E1v = (lane < 36) ? __expf(sscore[lane + 64]) : 0.f;
      float s  = wsum(E0 + E1v);
      float iv = rcpf_(s);
      sscore[lane] = E0 * iv;
      if (lane < 36) sscore[lane + 64] = E1v * iv;
    }
    __syncthreads();
    {
      float pc = 0.f;
      #pragma unroll
      for (int i = 0; i < 25; ++i) {
        int t = q4 * 25 + i;
        pc += sscore[t] * h2f(sXe[t * 128 + hh]);
      }
      spart[q4 * 128 + hh] = pc;
    }
    __syncthreads();
    {
      float v = 0.f;
      if (tid < 128) {
        float cx = spart[tid] + spart[tid + 128]
                 + spart[tid + 256] + spart[tid + 384];
        sctx[tid] = cx;
        v = fcwv * cx;
      }
      v = wsum(v);
      if (lane == 0 && wv < 2) sredY[wv] = v;
    }
    __syncthreads();
    {
      float yt = sredY[0] + sredY[1] + fcbv;
      float a0 = biasD + wihj * yt, a1 = 0.f, a2 = 0.f, a3 = 0.f;
      const uint4* hr = (const uint4*)(const u32*)shp;
      #pragma unroll
      for (int k = 0; k < 16; ++k) {
        uint4 hv = hr[k];
        a0 = dot2h(wpkD[4*k+0], hv.x, a0);
        a1 = dot2h(wpkD[4*k+1], hv.y, a1);
        a2 = dot2h(wpkD[4*k+2], hv.z, a2);
        a3 = dot2h(wpkD[4*k+3], hv.w, a3);
      }
      sg[tid] = (a0 + a1) + (a2 + a3);
    }
    __syncthreads();
    if (tid < 128) {
      float gi = sigm(sg[tid]);
      float gf = sigm(sg[tid + 128]);
      float gg = tanh_(sg[tid + 256]);
      float go = sigm(sg[tid + 384]);
      float c  = gf * sc[tid] + gi * gg;
      sc[tid]  = c;
      float d  = go * tanh_(c);
      sh[tid]  = d;
      shp[tid] = f2h(d);
      scp[tid] = f2h(c);
    }
    __syncthreads();
  }

  if (tid < C_) {
    float acc = fcfb[tid];
    const float* w = fcfW + (size_t)tid * 256;
    #pragma unroll 8
    for (int k = 0; k < 128; ++k)
      acc += w[k] * sh[k] + w[128 + k] * sctx[k];
    out[(size_t)b * C_ + tid] = acc;
  }
}

extern "C" void kernel_launch(void* const* d_in, const int* in_sizes, int n_in,
                              void* d_out, int out_size, void* d_ws, size_t ws_size,
                              hipStream_t stream) {
  (void)n_in; (void)out_size;
  const float* X    = (const float*)d_in[0];
  const float* eWih = (const float*)d_in[1];
  const float* eWhh = (const float*)d_in[2];
  const float* ebih = (const float*)d_in[3];
  const float* ebhh = (const float*)d_in[4];
  const float* eAw  = (const float*)d_in[5];
  const float* eAb  = (const float*)d_in[6];
  const float* dW1  = (const float*)d_in[7];
  const float* db1  = (const float*)d_in[8];
  const float* dW2  = (const float*)d_in[9];
  const float* db2  = (const float*)d_in[10];
  const float* dWih = (const float*)d_in[11];
  const float* dWhh = (const float*)d_in[12];
  const float* dbih = (const float*)d_in[13];
  const float* dbhh = (const float*)d_in[14];
  const float* fcW  = (const float*)d_in[15];
  const float* fcb  = (const float*)d_in[16];
  const float* fcfW = (const float*)d_in[17];
  const float* fcfb = (const float*)d_in[18];
  float* out = (float*)d_out;

  const int B = in_sizes[0] / (T_ * 128);
  const size_t needQ = (size_t)B * QS * sizeof(u16);
  if (ws_size >= needQ && (B % BPB) == 0) {
    darnn4<<<dim3(B / BPB), dim3(NT), 0, stream>>>(
        X, eWih, eWhh, ebih, ebhh, eAw, eAb,
        dW1, db1, dW2, db2, dWih, dWhh, dbih, dbhh,
        fcW, fcb, fcfW, fcfb, (u16*)d_ws, out);
  } else {
    darnn_fb<<<dim3(B), dim3(NTF), 0, stream>>>(
        X, eWih, eWhh, ebih, ebhh, eAw,
        dW1, db1, dW2, dWih, dWhh, dbih, dbhh,
        fcW, fcb, fcfW, fcfb, out);
  }
}

// Round 6
// 1233.611 us; speedup vs baseline: 1.5119x; 1.3795x over previous
//
#include <hip/hip_runtime.h>

// DA-RNN fused — R14: back to R8 structure; halve the S2 score stage.
//  * R13 verdict: 16 lockstep waves + 0 conflicts + 0 spills still ~52% VALU,
//    1701 us. Occupancy was never the lever; 2 independent pipelines/CU are
//    resource-infeasible (weights ~192 KB/pipeline). Attack WORK instead.
//  * R8 accounting: S2 (ptanh score) ~45% of runtime (128 ptanh x ~6 fp32 ops
//    + 3 LDS streams per thread per step).
//  * R14a: packed-fp16 S2 — E1 already fp16; u packed per step (su2), w2
//    packed once (sw2p); tanh via v_pk_* on 2 lanes; accumulate with
//    v_dot2_f32_f16. ~2x fewer S2 VALU ops; u/w2 reads become broadcasts.
//  * R14b: S0 butterfly — thread=(h=tid>>2, p=tid&3), partials reduced with
//    2 DPP shfl_xor + pair-pack via third; writes su2 directly. S1 stage and
//    one barrier removed (5 -> 4 barriers/decoder step).
//  * Everything else identical to R8 (512 thr, BPB=4, VGPR 128).

typedef unsigned int   u32;
typedef unsigned short u16;

#define T_  100
#define C_  32
#define NT  512
#define BPB 4
#define TS  132
#define QS  (T_ * NT)

typedef __attribute__((ext_vector_type(2))) __fp16 h16x2;

#if __has_builtin(__builtin_amdgcn_fdot2)
#define HAVE_FDOT2 1
#else
#define HAVE_FDOT2 0
#endif

__device__ __forceinline__ u32 pkh2(float a, float b) {
#if __has_builtin(__builtin_amdgcn_cvt_pkrtz)
  h16x2 p = __builtin_amdgcn_cvt_pkrtz(a, b);
  return __builtin_bit_cast(u32, p);
#else
  union { __fp16 h[2]; u32 u; } v;
  v.h[0] = (__fp16)a; v.h[1] = (__fp16)b;
  return v.u;
#endif
}
__device__ __forceinline__ void unph(u32 p, float& lo, float& hi) {
  union { u32 u; __fp16 h[2]; } v; v.u = p;
  lo = (float)v.h[0]; hi = (float)v.h[1];
}
__device__ __forceinline__ u16 f2h(float f) {
  union { __fp16 h; u16 u; } v; v.h = (__fp16)f; return v.u;
}
__device__ __forceinline__ float h2f(u16 u) {
  union { u16 u; __fp16 h; } v; v.u = u; return (float)v.h;
}
__device__ __forceinline__ float dot2h(u32 w, u32 x, float acc) {
#if HAVE_FDOT2
  return __builtin_amdgcn_fdot2(__builtin_bit_cast(h16x2, w),
                                __builtin_bit_cast(h16x2, x),
                                acc, false);
#else
  float a, b, c, d;
  unph(w, a, b); unph(x, c, d);
  return fmaf(a, c, fmaf(b, d, acc));
#endif
}

#if __has_builtin(__builtin_amdgcn_rcpf)
__device__ __forceinline__ float rcpf_(float x){ return __builtin_amdgcn_rcpf(x); }
#else
__device__ __forceinline__ float rcpf_(float x){ return 1.0f / x; }
#endif
__device__ __forceinline__ float sigm(float x){ return rcpf_(1.0f + __expf(-x)); }
__device__ __forceinline__ float tanh_(float x){
  return 1.0f - 2.0f * rcpf_(1.0f + __expf(2.0f * x));
}
__device__ __forceinline__ float ptanh(float x){
  x = fminf(1.0f, fmaxf(-1.0f, x));
  float x2 = x * x;
  float p  = fmaf(x2, 0.1333333f, -0.3333333f);
  return x * fmaf(x2, p, 1.0f);
}
// packed-fp16 tanh approx of (e+u), both packed half2 as u32
__device__ __forceinline__ u32 tanhpk(u32 eu, u32 uu) {
  h16x2 x = __builtin_bit_cast(h16x2, eu) + __builtin_bit_cast(h16x2, uu);
  const h16x2 one  = {(__fp16)1.0f,  (__fp16)1.0f};
#if __has_builtin(__builtin_elementwise_max) && __has_builtin(__builtin_elementwise_min)
  const h16x2 mone = {(__fp16)-1.0f, (__fp16)-1.0f};
  x = __builtin_elementwise_min(one, __builtin_elementwise_max(x, mone));
#else
  {
    float lo, hi; unph(__builtin_bit_cast(u32, x), lo, hi);
    x = (h16x2){(__fp16)fminf(1.f, fmaxf(-1.f, lo)),
                (__fp16)fminf(1.f, fmaxf(-1.f, hi))};
  }
#endif
  h16x2 x2 = x * x;
  const h16x2 c1 = {(__fp16)0.1333333f,  (__fp16)0.1333333f};
  const h16x2 c0 = {(__fp16)-0.3333333f, (__fp16)-0.3333333f};
  h16x2 r = x * (x2 * (x2 * c1 + c0) + one);
  return __builtin_bit_cast(u32, r);
}
__device__ __forceinline__ float wsum(float v){
  #pragma unroll
  for (int o = 32; o; o >>= 1) v += __shfl_xor(v, o, 64);
  return v;
}

// ============================ fast kernel (4 batches/block) =================
__global__ void __launch_bounds__(NT)
darnn4(const float* __restrict__ X,
       const float* __restrict__ eWih, const float* __restrict__ eWhh,
       const float* __restrict__ ebih, const float* __restrict__ ebhh,
       const float* __restrict__ eAw,  const float* __restrict__ eAb,
       const float* __restrict__ dW1,  const float* __restrict__ db1,
       const float* __restrict__ dW2,  const float* __restrict__ db2,
       const float* __restrict__ dWih, const float* __restrict__ dWhh,
       const float* __restrict__ dbih, const float* __restrict__ dbhh,
       const float* __restrict__ fcW,  const float* __restrict__ fcb,
       const float* __restrict__ fcfW, const float* __restrict__ fcfb,
       u16* __restrict__ qws,
       float* __restrict__ out)
{
  // LDS ~130.5 KB
  __shared__ __align__(16) u16   sE1[BPB][T_ * TS];  // x_tilde -> E1   105600
  __shared__ __align__(16) float sg[BPB][512];       //                  8192
  __shared__ __align__(16) float sh[BPB][128];       // h/d fp32         2048
  __shared__ __align__(16) float sc[BPB][128];       // c fp32           2048
  __shared__ __align__(16) u16   shp[BPB][128];      // h/d fp16         1024
  __shared__ __align__(16) u16   scp[BPB][128];      // c fp16           1024
  __shared__ __align__(16) float su[BPB][128];       // ctx              2048
  __shared__ __align__(16) float spart[BPB][512];    // partials         8192
  __shared__ __align__(16) float sye[BPB][128];      // ye -> beta       2048
  __shared__ __align__(16) u32   su2[BPB][64];       // packed u         1024
  __shared__ __align__(16) u32   sw2p[64];           // packed w2         256
  __shared__ float sred[16];

  const int tid  = threadIdx.x;
  const int lane = tid & 63;
  const int wv   = tid >> 6;     // 0..7
  const int hh   = tid & 127;
  const int q4   = tid >> 7;     // 0..3
  const int h4   = tid >> 2;     // 0..127 (S0 row)
  const int p4   = tid & 3;      // S0 column quarter
  const int b0   = blockIdx.x * BPB;

  (void)eAb; (void)db2;          // cancel under softmax shift-invariance

  if (tid < 64) sw2p[tid] = pkh2(dW2[2 * tid], dW2[2 * tid + 1]);

  // ---------- alpha (no max-sub; h/c terms cancel) + x_tilde ----------
  {
    const float* xp = X + (size_t)(b0 + q4) * 12800 + hh;
    float sval = 0.f;
    #pragma unroll 4
    for (int t = 0; t < T_; ++t) sval += xp[t * 128] * eAw[256 + t];
    float e = __expf(sval);
    float s = wsum(e);
    if (lane == 0) sred[wv] = s;
    __syncthreads();
    float al = e * rcpf_(sred[q4 * 2] + sred[q4 * 2 + 1]);
    #pragma unroll 4
    for (int t = 0; t < T_; ++t)
      sE1[q4][t * TS + hh] = f2h(al * xp[t * 128]);
    sh[q4][hh] = 0.f; sc[q4][hh] = 0.f; shp[q4][hh] = 0; scp[q4][hh] = 0;
  }
  __syncthreads();

  // ---------- Q GEMM: Q[b][t][r] = eWih[r,:]·x_tilde  (self-produced) ----
  {
    u32 wq[64];
    const float4* wi = (const float4*)(eWih + (size_t)tid * 128);
    #pragma unroll
    for (int i = 0; i < 32; ++i) {
      float4 v = wi[i];
      wq[2*i]   = pkh2(v.x, v.y);
      wq[2*i+1] = pkh2(v.z, v.w);
    }
    #pragma unroll 1
    for (int bg = 0; bg < BPB; ++bg) {
      u16* qb = qws + (size_t)(b0 + bg) * QS;
      #pragma unroll 1
      for (int t = 0; t < T_; ++t) {
        const uint2* xr = (const uint2*)(&sE1[bg][t * TS]);
        float a0 = 0.f, a1 = 0.f;
        #pragma unroll
        for (int k = 0; k < 16; ++k) {
          uint2 xv = xr[k];
          a0 = dot2h(wq[2*k],   xv.x, a0);
          a1 = dot2h(wq[2*k+1], xv.y, a1);
        }
        qb[t * NT + tid] = f2h(a0 + a1);
      }
    }
  }

  // ---------- encoder (2 barriers/step) ----------
  {
    u32 wpkH[64];
    const float4* wr = (const float4*)(eWhh + (size_t)tid * 128);
    #pragma unroll
    for (int i = 0; i < 32; ++i) {
      float4 v = wr[i];
      wpkH[2*i]   = pkh2(v.x, v.y);
      wpkH[2*i+1] = pkh2(v.z, v.w);
    }
    float biasg = ebih[tid] + ebhh[tid];

    u16 qc[BPB];
    #pragma unroll
    for (int bg = 0; bg < BPB; ++bg)
      qc[bg] = qws[(size_t)(b0 + bg) * QS + tid];

    for (int t = 0; t < T_; ++t) {
      u16 qn[BPB];
      #pragma unroll
      for (int bg = 0; bg < BPB; ++bg)
        qn[bg] = (t + 1 < T_) ? qws[(size_t)(b0 + bg) * QS + (t + 1) * NT + tid]
                              : (u16)0;
      #pragma unroll 1
      for (int bg = 0; bg < BPB; ++bg) {
        const uint4* hr = (const uint4*)(const u32*)shp[bg];
        float a0 = biasg + h2f(qc[bg]), a1 = 0.f, a2 = 0.f, a3 = 0.f;
        #pragma unroll
        for (int k = 0; k < 16; ++k) {
          uint4 hv = hr[k];
          a0 = dot2h(wpkH[4*k+0], hv.x, a0);
          a1 = dot2h(wpkH[4*k+1], hv.y, a1);
          a2 = dot2h(wpkH[4*k+2], hv.z, a2);
          a3 = dot2h(wpkH[4*k+3], hv.w, a3);
        }
        sg[bg][tid] = (a0 + a1) + (a2 + a3);
      }
      __syncthreads();
      {
        float gi = sigm(sg[q4][hh]);
        float gf = sigm(sg[q4][hh + 128]);
        float gg = tanh_(sg[q4][hh + 256]);
        float go = sigm(sg[q4][hh + 384]);
        float c  = gf * sc[q4][hh] + gi * gg;
        sc[q4][hh] = c;
        float h  = go * tanh_(c);
        sh[q4][hh] = h;
        u16 hb = f2h(h);
        shp[q4][hh] = hb;
        scp[q4][hh] = f2h(c);
        // Xe row t shares Q's slab (Q[t] already consumed; barrier-ordered)
        qws[(size_t)(b0 + q4) * QS + t * NT + hh] = hb;
      }
      __syncthreads();
      #pragma unroll
      for (int bg = 0; bg < BPB; ++bg) qc[bg] = qn[bg];
    }
  }

  // ---------- ye[t] = fcW · Xe[t]  ----------
  if (hh < T_) {
    #pragma unroll 1
    for (int bg = 0; bg < BPB; ++bg) {
      const uint2* xe = (const uint2*)(qws + (size_t)(b0 + bg) * QS
                                       + hh * NT + q4 * 32);
      const float* fw = fcW + q4 * 32;
      float a = 0.f;
      #pragma unroll
      for (int k = 0; k < 8; ++k) {
        uint2 xv = xe[k];
        float l0, l1, l2, l3;
        unph(xv.x, l0, l1); unph(xv.y, l2, l3);
        a += fw[4*k]*l0 + fw[4*k+1]*l1 + fw[4*k+2]*l2 + fw[4*k+3]*l3;
      }
      spart[bg][hh * 4 + q4] = a;
    }
  }
  __syncthreads();
  if (hh < T_) {
    float4 p = ((const float4*)spart[q4])[hh];
    sye[q4][hh] = (p.x + p.y) + (p.z + p.w);
  }
  __syncthreads();

  // ---------- E1[t][h] = dW1[h][256:384]·Xe[t] + db1[h] -> LDS ----------
  {
    u32 wtp[64];
    const float4* w4p = (const float4*)(dW1 + (size_t)hh * 384 + 256);
    #pragma unroll
    for (int i = 0; i < 32; ++i) {
      float4 v = w4p[i];
      wtp[2*i]   = pkh2(v.x, v.y);
      wtp[2*i+1] = pkh2(v.z, v.w);
    }
    float b1v = db1[hh];
    #pragma unroll 1
    for (int bg = 0; bg < BPB; ++bg) {
      #pragma unroll 1
      for (int i = 0; i < 25; ++i) {
        int t = q4 * 25 + i;
        const uint2* xe = (const uint2*)(qws + (size_t)(b0 + bg) * QS + t * NT);
        float a0 = 0.f, a1 = 0.f;
        #pragma unroll
        for (int k = 0; k < 16; ++k) {
          uint2 xv = xe[k];
          a0 = dot2h(wtp[2*k],   xv.x, a0);
          a1 = dot2h(wtp[2*k+1], xv.y, a1);
        }
        sE1[bg][t * TS + hh] = f2h(a0 + a1 + b1v);
      }
    }
  }

  // ---------- decoder weights ----------
  u32 wpkD[64];
  {
    const float4* wr = (const float4*)(dWhh + (size_t)tid * 128);
    #pragma unroll
    for (int i = 0; i < 32; ++i) {
      float4 v = wr[i];
      wpkD[2*i]   = pkh2(v.x, v.y);
      wpkD[2*i+1] = pkh2(v.z, v.w);
    }
  }
  u32 wtpU[32];   // dW1 row h4, z-cols [p4*64, p4*64+64)
  {
    const float4* wu = (const float4*)(dW1 + (size_t)h4 * 384 + p4 * 64);
    #pragma unroll
    for (int i = 0; i < 16; ++i) {
      float4 v = wu[i];
      wtpU[2*i]   = pkh2(v.x, v.y);
      wtpU[2*i+1] = pkh2(v.z, v.w);
    }
  }
  float biasD = dbih[tid] + dbhh[tid];
  float wihj  = dWih[tid];
  float fcbv  = fcb[0];
  sh[q4][hh] = 0.f; sc[q4][hh] = 0.f; shp[q4][hh] = 0; scp[q4][hh] = 0;
  __syncthreads();

  // ---------- decoder (4 barriers/step) ----------
  for (int step = 0; step < T_; ++step) {
    // S0: u[h4] partial over z-cols p4*64..+64; butterfly reduce in-wave;
    //     write packed su2[bg][h4>>1] (S1 stage + barrier eliminated)
    #pragma unroll 1
    for (int bg = 0; bg < BPB; ++bg) {
      const u32* bs = (p4 < 2) ? (const u32*)shp[bg] + (p4 & 1) * 32
                               : (const u32*)scp[bg] + (p4 & 1) * 32;
      const uint4* vp = (const uint4*)bs;
      float a0 = 0.f, a1 = 0.f;
      #pragma unroll
      for (int k = 0; k < 8; ++k) {
        uint4 v = vp[k];
        a0 = dot2h(wtpU[4*k+0], v.x, a0);
        a1 = dot2h(wtpU[4*k+1], v.y, a1);
        a0 = dot2h(wtpU[4*k+2], v.z, a0);
        a1 = dot2h(wtpU[4*k+3], v.w, a1);
      }
      float a = a0 + a1;
      a += __shfl_xor(a, 1, 64);
      a += __shfl_xor(a, 2, 64);          // all 4 lanes now hold u[h4]
      float b = __shfl_xor(a, 4, 64);     // partner row h4^1
      if ((tid & 7) == 0) su2[bg][h4 >> 1] = pkh2(a, b);
    }
    __syncthreads();
    // S2: score partials, packed fp16: thread (t=hh<100, quad q4), 32 h each
    if (hh < T_) {
      const uint2* wp  = (const uint2*)(sw2p + q4 * 16);
      const uint2* e0p = (const uint2*)(&sE1[0][hh * TS + q4 * 32]);
      const uint2* e1p = (const uint2*)(&sE1[1][hh * TS + q4 * 32]);
      const uint2* e2p = (const uint2*)(&sE1[2][hh * TS + q4 * 32]);
      const uint2* e3p = (const uint2*)(&sE1[3][hh * TS + q4 * 32]);
      const uint2* u0p = (const uint2*)(su2[0] + q4 * 16);
      const uint2* u1p = (const uint2*)(su2[1] + q4 * 16);
      const uint2* u2p = (const uint2*)(su2[2] + q4 * 16);
      const uint2* u3p = (const uint2*)(su2[3] + q4 * 16);
      float ac0 = 0.f, ac1 = 0.f, ac2 = 0.f, ac3 = 0.f;
      #pragma unroll
      for (int j = 0; j < 8; ++j) {
        uint2 w2v = wp[j];
        uint2 ev, uv;
        ev = e0p[j]; uv = u0p[j];
        ac0 = dot2h(w2v.x, tanhpk(ev.x, uv.x), ac0);
        ac0 = dot2h(w2v.y, tanhpk(ev.y, uv.y), ac0);
        ev = e1p[j]; uv = u1p[j];
        ac1 = dot2h(w2v.x, tanhpk(ev.x, uv.x), ac1);
        ac1 = dot2h(w2v.y, tanhpk(ev.y, uv.y), ac1);
        ev = e2p[j]; uv = u2p[j];
        ac2 = dot2h(w2v.x, tanhpk(ev.x, uv.x), ac2);
        ac2 = dot2h(w2v.y, tanhpk(ev.y, uv.y), ac2);
        ev = e3p[j]; uv = u3p[j];
        ac3 = dot2h(w2v.x, tanhpk(ev.x, uv.x), ac3);
        ac3 = dot2h(w2v.y, tanhpk(ev.y, uv.y), ac3);
      }
      spart[0][hh * 4 + q4] = ac0;
      spart[1][hh * 4 + q4] = ac1;
      spart[2][hh * 4 + q4] = ac2;
      spart[3][hh * 4 + q4] = ac3;
    }
    __syncthreads();
    // S3: softmax over t + y, wave-redundant (no barrier after)
    float yv[BPB];
    #pragma unroll
    for (int bg = 0; bg < BPB; ++bg) {
      float4 p0 = ((const float4*)spart[bg])[lane];
      float e0 = __expf((p0.x + p0.y) + (p0.z + p0.w));
      float es = e0, ys = e0 * sye[bg][lane];
      if (lane < 36) {
        float4 p1 = ((const float4*)spart[bg])[64 + lane];
        float e1 = __expf((p1.x + p1.y) + (p1.z + p1.w));
        es += e1; ys += e1 * sye[bg][64 + lane];
      }
      es = wsum(es); ys = wsum(ys);
      yv[bg] = ys * rcpf_(es) + fcbv;
    }
    // S6: gates
    #pragma unroll 1
    for (int bg = 0; bg < BPB; ++bg) {
      const uint4* hr = (const uint4*)(const u32*)shp[bg];
      float a0 = biasD + wihj * yv[bg], a1 = 0.f, a2 = 0.f, a3 = 0.f;
      #pragma unroll
      for (int k = 0; k < 16; ++k) {
        uint4 hv = hr[k];
        a0 = dot2h(wpkD[4*k+0], hv.x, a0);
        a1 = dot2h(wpkD[4*k+1], hv.y, a1);
        a2 = dot2h(wpkD[4*k+2], hv.z, a2);
        a3 = dot2h(wpkD[4*k+3], hv.w, a3);
      }
      sg[bg][tid] = (a0 + a1) + (a2 + a3);
    }
    __syncthreads();
    // S7: pointwise LSTM (all 4 batches, full block)
    {
      float gi = sigm(sg[q4][hh]);
      float gf = sigm(sg[q4][hh + 128]);
      float gg = tanh_(sg[q4][hh + 256]);
      float go = sigm(sg[q4][hh + 384]);
      float c  = gf * sc[q4][hh] + gi * gg;
      sc[q4][hh] = c;
      float d  = go * tanh_(c);
      sh[q4][hh] = d;
      shp[q4][hh] = f2h(d);
      scp[q4][hh] = f2h(c);
    }
    __syncthreads();
  }

  // ---------- final beta -> ctx -> head ----------
  if (wv < BPB) {                     // wave w computes beta for batch w
    int bg = wv;
    float4 p0 = ((const float4*)spart[bg])[lane];
    float e0 = __expf((p0.x + p0.y) + (p0.z + p0.w));
    float e1 = 0.f;
    if (lane < 36) {
      float4 p1 = ((const float4*)spart[bg])[64 + lane];
      e1 = __expf((p1.x + p1.y) + (p1.z + p1.w));
    }
    float iv = rcpf_(wsum(e0 + e1));
    sye[bg][lane] = e0 * iv;          // overwrite ye with beta
    if (lane < 36) sye[bg][64 + lane] = e1 * iv;
  }
  __syncthreads();
  {
    const u16* xeb = qws + (size_t)(b0 + q4) * QS + hh;
    float cx = 0.f;
    #pragma unroll 4
    for (int t = 0; t < T_; ++t)
      cx += sye[q4][t] * h2f(xeb[t * NT]);
    su[q4][hh] = cx;                  // ctx
  }
  __syncthreads();
  if (tid < BPB * C_) {
    int bg = tid >> 5, cls = tid & 31;
    const float* w = fcfW + (size_t)cls * 256;
    float acc = fcfb[cls];
    #pragma unroll 8
    for (int k = 0; k < 128; ++k)
      acc += w[k] * sh[bg][k] + w[128 + k] * su[bg][k];
    out[(size_t)(b0 + bg) * C_ + cls] = acc;
  }
}

// ================== fallback (R7 structure, no workspace) ==================
__global__ void __launch_bounds__(NT)
darnn_fb(const float* __restrict__ X,
         const float* __restrict__ eWih, const float* __restrict__ eWhh,
         const float* __restrict__ ebih, const float* __restrict__ ebhh,
         const float* __restrict__ eAw,
         const float* __restrict__ dW1,  const float* __restrict__ db1,
         const float* __restrict__ dW2,
         const float* __restrict__ dWih, const float* __restrict__ dWhh,
         const float* __restrict__ dbih, const float* __restrict__ dbhh,
         const float* __restrict__ fcW,  const float* __restrict__ fcb,
         const float* __restrict__ fcfW, const float* __restrict__ fcfb,
         float* __restrict__ out)
{
  __shared__ __align__(16) u16   sxh[12800];
  __shared__ __align__(16) u16   sXe[12800];
  __shared__ __align__(16) float sg[512];
  __shared__ __align__(16) float sh[128];
  __shared__ __align__(16) float sc[128];
  __shared__ __align__(16) u16   shp[128];
  __shared__ __align__(16) u16   scp[128];
  __shared__ __align__(16) float su[128];
  __shared__ __align__(16) float spart[512];
  __shared__ __align__(16) float sscore[128];
  __shared__ __align__(16) float sctx[128];
  __shared__ float sred[8];
  __shared__ float sredY[2];

  const int tid  = threadIdx.x;
  const int lane = tid & 63;
  const int wv   = tid >> 6;
  const int b    = blockIdx.x;
  const int hh   = tid & 127;
  const int q4   = tid >> 7;

  {
    const float4* Xb4 = (const float4*)(X + (size_t)b * 12800);
    u32* dst = (u32*)sxh;
    #pragma unroll
    for (int i = 0; i < 7; ++i) {
      int idx = tid + NT * i;
      if (idx < 3200) {
        float4 v = Xb4[idx];
        dst[2*idx]   = pkh2(v.x, v.y);
        dst[2*idx+1] = pkh2(v.z, v.w);
      }
    }
  }
  __syncthreads();
  float sval = 0.f;
  if (tid < 128) {
    #pragma unroll 4
    for (int t = 0; t < T_; ++t)
      sval += h2f(sxh[t * 128 + tid]) * eAw[256 + t];
  }
  float ee = (tid < 128) ? __expf(sval) : 0.f;
  float sm = wsum(ee);
  if (lane == 0 && wv < 2) sred[2 + wv] = sm;
  __syncthreads();
  if (tid < 128) {
    su[tid] = ee * rcpf_(sred[2] + sred[3]);
    sh[tid] = 0.f; sc[tid] = 0.f; shp[tid] = 0; scp[tid] = 0;
  }
  __syncthreads();
  {
    u32* sx32 = (u32*)sxh;
    #pragma unroll
    for (int i = 0; i < 13; ++i) {
      int p = tid + NT * i;
      if (p < 6400) {
        float lo, hi; unph(sx32[p], lo, hi);
        int m = (2 * p) & 127;
        sx32[p] = pkh2(lo * su[m], hi * su[m + 1]);
      }
    }
  }
  __syncthreads();

  u32 wpkH[64], wpkI[64];
  {
    const float4* wr = (const float4*)(eWhh + (size_t)tid * 128);
    #pragma unroll
    for (int i = 0; i < 32; ++i) {
      float4 v = wr[i];
      wpkH[2*i] = pkh2(v.x, v.y); wpkH[2*i+1] = pkh2(v.z, v.w);
    }
    const float4* wi = (const float4*)(eWih + (size_t)tid * 128);
    #pragma unroll
    for (int i = 0; i < 32; ++i) {
      float4 v = wi[i];
      wpkI[2*i] = pkh2(v.x, v.y); wpkI[2*i+1] = pkh2(v.z, v.w);
    }
  }
  float biasg = ebih[tid] + ebhh[tid];

  for (int t = 0; t < T_; ++t) {
    float a0 = biasg, a1 = 0.f, a2 = 0.f, a3 = 0.f;
    const uint4* hr = (const uint4*)(const u32*)shp;
    #pragma unroll
    for (int k = 0; k < 16; ++k) {
      uint4 hv = hr[k];
      a0 = dot2h(wpkH[4*k+0], hv.x, a0);
      a1 = dot2h(wpkH[4*k+1], hv.y, a1);
      a2 = dot2h(wpkH[4*k+2], hv.z, a2);
      a3 = dot2h(wpkH[4*k+3], hv.w, a3);
    }
    const uint4* xr = (const uint4*)((const u32*)sxh + t * 64);
    #pragma unroll
    for (int k = 0; k < 16; ++k) {
      uint4 xv = xr[k];
      a0 = dot2h(wpkI[4*k+0], xv.x, a0);
      a1 = dot2h(wpkI[4*k+1], xv.y, a1);
      a2 = dot2h(wpkI[4*k+2], xv.z, a2);
      a3 = dot2h(wpkI[4*k+3], xv.w, a3);
    }
    sg[tid] = (a0 + a1) + (a2 + a3);
    __syncthreads();
    if (tid < 128) {
      float gi = sigm(sg[tid]);
      float gf = sigm(sg[tid + 128]);
      float gg = tanh_(sg[tid + 256]);
      float go = sigm(sg[tid + 384]);
      float c  = gf * sc[tid] + gi * gg;
      sc[tid]  = c;
      float h  = go * tanh_(c);
      sh[tid]  = h;
      u16 hb = f2h(h);
      shp[tid] = hb; scp[tid] = f2h(c);
      sXe[t * 128 + tid] = hb;
    }
    __syncthreads();
  }

  {
    u32 wtp[64];
    const float4* w4 = (const float4*)(dW1 + (size_t)hh * 384 + 256);
    #pragma unroll
    for (int i = 0; i < 32; ++i) {
      float4 v = w4[i];
      wtp[2*i] = pkh2(v.x, v.y); wtp[2*i+1] = pkh2(v.z, v.w);
    }
    float b1v = db1[hh];
    u16 e1out[25];
    #pragma unroll 1
    for (int i = 0; i < 25; ++i) {
      int t = q4 * 25 + i;
      const uint4* xe4 = (const uint4*)(sXe + t * 128);
      float a0 = 0.f, a1 = 0.f;
      #pragma unroll
      for (int k = 0; k < 16; ++k) {
        uint4 xv = xe4[k];
        a0 = dot2h(wtp[4*k+0], xv.x, a0);
        a1 = dot2h(wtp[4*k+1], xv.y, a1);
        a0 = dot2h(wtp[4*k+2], xv.z, a0);
        a1 = dot2h(wtp[4*k+3], xv.w, a1);
      }
      e1out[i] = f2h(a0 + a1 + b1v);
    }
    __syncthreads();
    #pragma unroll 1
    for (int i = 0; i < 25; ++i)
      sxh[(q4 * 25 + i) * 128 + hh] = e1out[i];
  }

  u32 wpkD[64];
  {
    const float4* wr = (const float4*)(dWhh + (size_t)tid * 128);
    #pragma unroll
    for (int i = 0; i < 32; ++i) {
      float4 v = wr[i];
      wpkD[2*i] = pkh2(v.x, v.y); wpkD[2*i+1] = pkh2(v.z, v.w);
    }
  }
  u32 wtpU[32];
  {
    const float4* wu = (const float4*)(dW1 + (size_t)hh * 384 + q4 * 64);
    #pragma unroll
    for (int i = 0; i < 16; ++i) {
      float4 v = wu[i];
      wtpU[2*i] = pkh2(v.x, v.y); wtpU[2*i+1] = pkh2(v.z, v.w);
    }
  }
  float biasD = dbih[tid] + dbhh[tid];
  float wihj  = dWih[tid];
  float w2a   = dW2[lane];
  float w2b   = dW2[lane + 64];
  float fcbv  = fcb[0];
  float fcwv  = (tid < 128) ? fcW[tid] : 0.f;
  if (tid < 128) { sh[tid] = 0.f; sc[tid] = 0.f; shp[tid] = 0; scp[tid] = 0; }
  __syncthreads();

  for (int step = 0; step < T_; ++step) {
    {
      const u32* base = (q4 < 2) ? (const u32*)shp : (const u32*)scp;
      const uint4* vp = (const uint4*)(base + (q4 & 1) * 32);
      float a0 = 0.f, a1 = 0.f;
      #pragma unroll
      for (int k = 0; k < 8; ++k) {
        uint4 v = vp[k];
        a0 = dot2h(wtpU[4*k+0], v.x, a0);
        a1 = dot2h(wtpU[4*k+1], v.y, a1);
        a0 = dot2h(wtpU[4*k+2], v.z, a0);
        a1 = dot2h(wtpU[4*k+3], v.w, a1);
      }
      spart[q4 * 128 + hh] = a0 + a1;
    }
    __syncthreads();
    {
      float ul = spart[lane] + spart[128 + lane]
               + spart[256 + lane] + spart[384 + lane];
      float uh = spart[64 + lane] + spart[192 + lane]
               + spart[320 + lane] + spart[448 + lane];
      #pragma unroll 1
      for (int i = 0; i < 13; ++i) {
        int t = wv + 8 * i;
        if (t < T_) {
          float v = w2a * ptanh(h2f(sxh[t * 128 + lane]) + ul)
                  + w2b * ptanh(h2f(sxh[t * 128 + 64 + lane]) + uh);
          v = wsum(v);
          if (lane == 0) sscore[t] = v;
        }
      }
    }
    __syncthreads();
    if (wv == 0) {
      float s0 = sscore[lane];
      float E0 = __expf(s0);
      float E1v = (lane < 36) ? __expf(sscore[lane + 64]) : 0.f;
      float s  = wsum(E0 + E1v);
      float iv = rcpf_(s);
      sscore[lane] = E0 * iv;
      if (lane < 36) sscore[lane + 64] = E1v * iv;
    }
    __syncthreads();
    {
      float pc = 0.f;
      #pragma unroll
      for (int i = 0; i < 25; ++i) {
        int t = q4 * 25 + i;
        pc += sscore[t] * h2f(sXe[t * 128 + hh]);
      }
      spart[q4 * 128 + hh] = pc;
    }
    __syncthreads();
    {
      float v = 0.f;
      if (tid < 128) {
        float cx = spart[tid] + spart[tid + 128]
                 + spart[tid + 256] + spart[tid + 384];
        sctx[tid] = cx;
        v = fcwv * cx;
      }
      v = wsum(v);
      if (lane == 0 && wv < 2) sredY[wv] = v;
    }
    __syncthreads();
    {
      float yt = sredY[0] + sredY[1] + fcbv;
      float a0 = biasD + wihj * yt, a1 = 0.f, a2 = 0.f, a3 = 0.f;
      const uint4* hr = (const uint4*)(const u32*)shp;
      #pragma unroll
      for (int k = 0; k < 16; ++k) {
        uint4 hv = hr[k];
        a0 = dot2h(wpkD[4*k+0], hv.x, a0);
        a1 = dot2h(wpkD[4*k+1], hv.y, a1);
        a2 = dot2h(wpkD[4*k+2], hv.z, a2);
        a3 = dot2h(wpkD[4*k+3], hv.w, a3);
      }
      sg[tid] = (a0 + a1) + (a2 + a3);
    }
    __syncthreads();
    if (tid < 128) {
      float gi = sigm(sg[tid]);
      float gf = sigm(sg[tid + 128]);
      float gg = tanh_(sg[tid + 256]);
      float go = sigm(sg[tid + 384]);
      float c  = gf * sc[tid] + gi * gg;
      sc[tid]  = c;
      float d  = go * tanh_(c);
      sh[tid]  = d;
      shp[tid] = f2h(d);
      scp[tid] = f2h(c);
    }
    __syncthreads();
  }

  if (tid < C_) {
    float acc = fcfb[tid];
    const float* w = fcfW + (size_t)tid * 256;
    #pragma unroll 8
    for (int k = 0; k < 128; ++k)
      acc += w[k] * sh[k] + w[128 + k] * sctx[k];
    out[(size_t)b * C_ + tid] = acc;
  }
}

extern "C" void kernel_launch(void* const* d_in, const int* in_sizes, int n_in,
                              void* d_out, int out_size, void* d_ws, size_t ws_size,
                              hipStream_t stream) {
  (void)n_in; (void)out_size;
  const float* X    = (const float*)d_in[0];
  const float* eWih = (const float*)d_in[1];
  const float* eWhh = (const float*)d_in[2];
  const float* ebih = (const float*)d_in[3];
  const float* ebhh = (const float*)d_in[4];
  const float* eAw  = (const float*)d_in[5];
  const float* eAb  = (const float*)d_in[6];
  const float* dW1  = (const float*)d_in[7];
  const float* db1  = (const float*)d_in[8];
  const float* dW2  = (const float*)d_in[9];
  const float* db2  = (const float*)d_in[10];
  const float* dWih = (const float*)d_in[11];
  const float* dWhh = (const float*)d_in[12];
  const float* dbih = (const float*)d_in[13];
  const float* dbhh = (const float*)d_in[14];
  const float* fcW  = (const float*)d_in[15];
  const float* fcb  = (const float*)d_in[16];
  const float* fcfW = (const float*)d_in[17];
  const float* fcfb = (const float*)d_in[18];
  float* out = (float*)d_out;

  const int B = in_sizes[0] / (T_ * 128);
  const size_t needQ = (size_t)B * QS * sizeof(u16);
  if (ws_size >= needQ && (B % BPB) == 0) {
    darnn4<<<dim3(B / BPB), dim3(NT), 0, stream>>>(
        X, eWih, eWhh, ebih, ebhh, eAw, eAb,
        dW1, db1, dW2, db2, dWih, dWhh, dbih, dbhh,
        fcW, fcb, fcfW, fcfb, (u16*)d_ws, out);
  } else {
    darnn_fb<<<dim3(B), dim3(NT), 0, stream>>>(
        X, eWih, eWhh, ebih, ebhh, eAw,
        dW1, db1, dW2, dWih, dWhh, dbih, dbhh,
        fcW, fcb, fcfW, fcfb, out);
  }
}

// Round 7
// 1126.732 us; speedup vs baseline: 1.6554x; 1.0949x over previous
//
#include <hip/hip_runtime.h>

// DA-RNN fused — R15: R14 + conflict-free S0 + slim S3.
//  * R14 post-mortem: −88 us (1321->1233) but SQ_LDS_BANK_CONFLICT 3.7M->29.9M.
//    Source: S0's (h4,p4) remap put 4 distinct addrs per wave instr, all four
//    bases bank-0-aligned -> 4-way serialization on every S0 ds_read_b128.
//  * R15a: S0 segment rotation k=(kk+2*p4)&7 with pre-rotated wtpU (register
//    indices stay compile-time). Groups hit banks 4kk+8*p4 -> disjoint.
//  * R15b: S3 computes softmax/y only for bg=q4 (own quad; 2-way redundancy,
//    was 8-way x4 bg). y-term moved out of S6 (rank-1) into S7 via 4 preloaded
//    dWih rows: gates += wi{x,y,z,w}*yv. yv flows S3->S7 in-register; no new
//    barrier.
//  * Everything else identical to R14 (512 thr, BPB=4, packed-fp16 S2).

typedef unsigned int   u32;
typedef unsigned short u16;

#define T_  100
#define C_  32
#define NT  512
#define BPB 4
#define TS  132
#define QS  (T_ * NT)

typedef __attribute__((ext_vector_type(2))) __fp16 h16x2;

#if __has_builtin(__builtin_amdgcn_fdot2)
#define HAVE_FDOT2 1
#else
#define HAVE_FDOT2 0
#endif

__device__ __forceinline__ u32 pkh2(float a, float b) {
#if __has_builtin(__builtin_amdgcn_cvt_pkrtz)
  h16x2 p = __builtin_amdgcn_cvt_pkrtz(a, b);
  return __builtin_bit_cast(u32, p);
#else
  union { __fp16 h[2]; u32 u; } v;
  v.h[0] = (__fp16)a; v.h[1] = (__fp16)b;
  return v.u;
#endif
}
__device__ __forceinline__ void unph(u32 p, float& lo, float& hi) {
  union { u32 u; __fp16 h[2]; } v; v.u = p;
  lo = (float)v.h[0]; hi = (float)v.h[1];
}
__device__ __forceinline__ u16 f2h(float f) {
  union { __fp16 h; u16 u; } v; v.h = (__fp16)f; return v.u;
}
__device__ __forceinline__ float h2f(u16 u) {
  union { u16 u; __fp16 h; } v; v.u = u; return (float)v.h;
}
__device__ __forceinline__ float dot2h(u32 w, u32 x, float acc) {
#if HAVE_FDOT2
  return __builtin_amdgcn_fdot2(__builtin_bit_cast(h16x2, w),
                                __builtin_bit_cast(h16x2, x),
                                acc, false);
#else
  float a, b, c, d;
  unph(w, a, b); unph(x, c, d);
  return fmaf(a, c, fmaf(b, d, acc));
#endif
}

#if __has_builtin(__builtin_amdgcn_rcpf)
__device__ __forceinline__ float rcpf_(float x){ return __builtin_amdgcn_rcpf(x); }
#else
__device__ __forceinline__ float rcpf_(float x){ return 1.0f / x; }
#endif
__device__ __forceinline__ float sigm(float x){ return rcpf_(1.0f + __expf(-x)); }
__device__ __forceinline__ float tanh_(float x){
  return 1.0f - 2.0f * rcpf_(1.0f + __expf(2.0f * x));
}
__device__ __forceinline__ float ptanh(float x){
  x = fminf(1.0f, fmaxf(-1.0f, x));
  float x2 = x * x;
  float p  = fmaf(x2, 0.1333333f, -0.3333333f);
  return x * fmaf(x2, p, 1.0f);
}
// packed-fp16 tanh approx of (e+u), both packed half2 as u32
__device__ __forceinline__ u32 tanhpk(u32 eu, u32 uu) {
  h16x2 x = __builtin_bit_cast(h16x2, eu) + __builtin_bit_cast(h16x2, uu);
  const h16x2 one  = {(__fp16)1.0f,  (__fp16)1.0f};
#if __has_builtin(__builtin_elementwise_max) && __has_builtin(__builtin_elementwise_min)
  const h16x2 mone = {(__fp16)-1.0f, (__fp16)-1.0f};
  x = __builtin_elementwise_min(one, __builtin_elementwise_max(x, mone));
#else
  {
    float lo, hi; unph(__builtin_bit_cast(u32, x), lo, hi);
    x = (h16x2){(__fp16)fminf(1.f, fmaxf(-1.f, lo)),
                (__fp16)fminf(1.f, fmaxf(-1.f, hi))};
  }
#endif
  h16x2 x2 = x * x;
  const h16x2 c1 = {(__fp16)0.1333333f,  (__fp16)0.1333333f};
  const h16x2 c0 = {(__fp16)-0.3333333f, (__fp16)-0.3333333f};
  h16x2 r = x * (x2 * (x2 * c1 + c0) + one);
  return __builtin_bit_cast(u32, r);
}
__device__ __forceinline__ float wsum(float v){
  #pragma unroll
  for (int o = 32; o; o >>= 1) v += __shfl_xor(v, o, 64);
  return v;
}

// ============================ fast kernel (4 batches/block) =================
__global__ void __launch_bounds__(NT)
darnn4(const float* __restrict__ X,
       const float* __restrict__ eWih, const float* __restrict__ eWhh,
       const float* __restrict__ ebih, const float* __restrict__ ebhh,
       const float* __restrict__ eAw,  const float* __restrict__ eAb,
       const float* __restrict__ dW1,  const float* __restrict__ db1,
       const float* __restrict__ dW2,  const float* __restrict__ db2,
       const float* __restrict__ dWih, const float* __restrict__ dWhh,
       const float* __restrict__ dbih, const float* __restrict__ dbhh,
       const float* __restrict__ fcW,  const float* __restrict__ fcb,
       const float* __restrict__ fcfW, const float* __restrict__ fcfb,
       u16* __restrict__ qws,
       float* __restrict__ out)
{
  // LDS ~130.5 KB
  __shared__ __align__(16) u16   sE1[BPB][T_ * TS];  // x_tilde -> E1   105600
  __shared__ __align__(16) float sg[BPB][512];       //                  8192
  __shared__ __align__(16) float sh[BPB][128];       // h/d fp32         2048
  __shared__ __align__(16) float sc[BPB][128];       // c fp32           2048
  __shared__ __align__(16) u16   shp[BPB][128];      // h/d fp16         1024
  __shared__ __align__(16) u16   scp[BPB][128];      // c fp16           1024
  __shared__ __align__(16) float su[BPB][128];       // ctx              2048
  __shared__ __align__(16) float spart[BPB][512];    // partials         8192
  __shared__ __align__(16) float sye[BPB][128];      // ye -> beta       2048
  __shared__ __align__(16) u32   su2[BPB][64];       // packed u         1024
  __shared__ __align__(16) u32   sw2p[64];           // packed w2         256
  __shared__ float sred[16];

  const int tid  = threadIdx.x;
  const int lane = tid & 63;
  const int wv   = tid >> 6;     // 0..7
  const int hh   = tid & 127;
  const int q4   = tid >> 7;     // 0..3
  const int h4   = tid >> 2;     // 0..127 (S0 row)
  const int p4   = tid & 3;      // S0 column quarter
  const int b0   = blockIdx.x * BPB;

  (void)eAb; (void)db2;          // cancel under softmax shift-invariance

  if (tid < 64) sw2p[tid] = pkh2(dW2[2 * tid], dW2[2 * tid + 1]);

  // ---------- alpha (no max-sub; h/c terms cancel) + x_tilde ----------
  {
    const float* xp = X + (size_t)(b0 + q4) * 12800 + hh;
    float sval = 0.f;
    #pragma unroll 4
    for (int t = 0; t < T_; ++t) sval += xp[t * 128] * eAw[256 + t];
    float e = __expf(sval);
    float s = wsum(e);
    if (lane == 0) sred[wv] = s;
    __syncthreads();
    float al = e * rcpf_(sred[q4 * 2] + sred[q4 * 2 + 1]);
    #pragma unroll 4
    for (int t = 0; t < T_; ++t)
      sE1[q4][t * TS + hh] = f2h(al * xp[t * 128]);
    sh[q4][hh] = 0.f; sc[q4][hh] = 0.f; shp[q4][hh] = 0; scp[q4][hh] = 0;
  }
  __syncthreads();

  // ---------- Q GEMM: Q[b][t][r] = eWih[r,:]·x_tilde  (self-produced) ----
  {
    u32 wq[64];
    const float4* wi = (const float4*)(eWih + (size_t)tid * 128);
    #pragma unroll
    for (int i = 0; i < 32; ++i) {
      float4 v = wi[i];
      wq[2*i]   = pkh2(v.x, v.y);
      wq[2*i+1] = pkh2(v.z, v.w);
    }
    #pragma unroll 1
    for (int bg = 0; bg < BPB; ++bg) {
      u16* qb = qws + (size_t)(b0 + bg) * QS;
      #pragma unroll 1
      for (int t = 0; t < T_; ++t) {
        const uint2* xr = (const uint2*)(&sE1[bg][t * TS]);
        float a0 = 0.f, a1 = 0.f;
        #pragma unroll
        for (int k = 0; k < 16; ++k) {
          uint2 xv = xr[k];
          a0 = dot2h(wq[2*k],   xv.x, a0);
          a1 = dot2h(wq[2*k+1], xv.y, a1);
        }
        qb[t * NT + tid] = f2h(a0 + a1);
      }
    }
  }

  // ---------- encoder (2 barriers/step) ----------
  {
    u32 wpkH[64];
    const float4* wr = (const float4*)(eWhh + (size_t)tid * 128);
    #pragma unroll
    for (int i = 0; i < 32; ++i) {
      float4 v = wr[i];
      wpkH[2*i]   = pkh2(v.x, v.y);
      wpkH[2*i+1] = pkh2(v.z, v.w);
    }
    float biasg = ebih[tid] + ebhh[tid];

    u16 qc[BPB];
    #pragma unroll
    for (int bg = 0; bg < BPB; ++bg)
      qc[bg] = qws[(size_t)(b0 + bg) * QS + tid];

    for (int t = 0; t < T_; ++t) {
      u16 qn[BPB];
      #pragma unroll
      for (int bg = 0; bg < BPB; ++bg)
        qn[bg] = (t + 1 < T_) ? qws[(size_t)(b0 + bg) * QS + (t + 1) * NT + tid]
                              : (u16)0;
      #pragma unroll 1
      for (int bg = 0; bg < BPB; ++bg) {
        const uint4* hr = (const uint4*)(const u32*)shp[bg];
        float a0 = biasg + h2f(qc[bg]), a1 = 0.f, a2 = 0.f, a3 = 0.f;
        #pragma unroll
        for (int k = 0; k < 16; ++k) {
          uint4 hv = hr[k];
          a0 = dot2h(wpkH[4*k+0], hv.x, a0);
          a1 = dot2h(wpkH[4*k+1], hv.y, a1);
          a2 = dot2h(wpkH[4*k+2], hv.z, a2);
          a3 = dot2h(wpkH[4*k+3], hv.w, a3);
        }
        sg[bg][tid] = (a0 + a1) + (a2 + a3);
      }
      __syncthreads();
      {
        float gi = sigm(sg[q4][hh]);
        float gf = sigm(sg[q4][hh + 128]);
        float gg = tanh_(sg[q4][hh + 256]);
        float go = sigm(sg[q4][hh + 384]);
        float c  = gf * sc[q4][hh] + gi * gg;
        sc[q4][hh] = c;
        float h  = go * tanh_(c);
        sh[q4][hh] = h;
        u16 hb = f2h(h);
        shp[q4][hh] = hb;
        scp[q4][hh] = f2h(c);
        // Xe row t shares Q's slab (Q[t] already consumed; barrier-ordered)
        qws[(size_t)(b0 + q4) * QS + t * NT + hh] = hb;
      }
      __syncthreads();
      #pragma unroll
      for (int bg = 0; bg < BPB; ++bg) qc[bg] = qn[bg];
    }
  }

  // ---------- ye[t] = fcW · Xe[t]  ----------
  if (hh < T_) {
    #pragma unroll 1
    for (int bg = 0; bg < BPB; ++bg) {
      const uint2* xe = (const uint2*)(qws + (size_t)(b0 + bg) * QS
                                       + hh * NT + q4 * 32);
      const float* fw = fcW + q4 * 32;
      float a = 0.f;
      #pragma unroll
      for (int k = 0; k < 8; ++k) {
        uint2 xv = xe[k];
        float l0, l1, l2, l3;
        unph(xv.x, l0, l1); unph(xv.y, l2, l3);
        a += fw[4*k]*l0 + fw[4*k+1]*l1 + fw[4*k+2]*l2 + fw[4*k+3]*l3;
      }
      spart[bg][hh * 4 + q4] = a;
    }
  }
  __syncthreads();
  if (hh < T_) {
    float4 p = ((const float4*)spart[q4])[hh];
    sye[q4][hh] = (p.x + p.y) + (p.z + p.w);
  }
  __syncthreads();

  // ---------- E1[t][h] = dW1[h][256:384]·Xe[t] + db1[h] -> LDS ----------
  {
    u32 wtp[64];
    const float4* w4p = (const float4*)(dW1 + (size_t)hh * 384 + 256);
    #pragma unroll
    for (int i = 0; i < 32; ++i) {
      float4 v = w4p[i];
      wtp[2*i]   = pkh2(v.x, v.y);
      wtp[2*i+1] = pkh2(v.z, v.w);
    }
    float b1v = db1[hh];
    #pragma unroll 1
    for (int bg = 0; bg < BPB; ++bg) {
      #pragma unroll 1
      for (int i = 0; i < 25; ++i) {
        int t = q4 * 25 + i;
        const uint2* xe = (const uint2*)(qws + (size_t)(b0 + bg) * QS + t * NT);
        float a0 = 0.f, a1 = 0.f;
        #pragma unroll
        for (int k = 0; k < 16; ++k) {
          uint2 xv = xe[k];
          a0 = dot2h(wtp[2*k],   xv.x, a0);
          a1 = dot2h(wtp[2*k+1], xv.y, a1);
        }
        sE1[bg][t * TS + hh] = f2h(a0 + a1 + b1v);
      }
    }
  }

  // ---------- decoder weights ----------
  u32 wpkD[64];
  {
    const float4* wr = (const float4*)(dWhh + (size_t)tid * 128);
    #pragma unroll
    for (int i = 0; i < 32; ++i) {
      float4 v = wr[i];
      wpkD[2*i]   = pkh2(v.x, v.y);
      wpkD[2*i+1] = pkh2(v.z, v.w);
    }
  }
  // S0 weights, segment-rotated: wtpU[4*kk..] holds z-cols
  // [p4*64 + 8*k, +8) with k=(kk+2*p4)&7 -> reads hit disjoint banks.
  u32 wtpU[32];
  {
    const float4* wu = (const float4*)(dW1 + (size_t)h4 * 384 + p4 * 64);
    #pragma unroll
    for (int kk = 0; kk < 8; ++kk) {
      int k = (kk + 2 * p4) & 7;
      float4 v0 = wu[2*k], v1 = wu[2*k + 1];
      wtpU[4*kk+0] = pkh2(v0.x, v0.y);
      wtpU[4*kk+1] = pkh2(v0.z, v0.w);
      wtpU[4*kk+2] = pkh2(v1.x, v1.y);
      wtpU[4*kk+3] = pkh2(v1.z, v1.w);
    }
  }
  float biasD = dbih[tid] + dbhh[tid];
  // dWih rows for the S7 y-injection (thread covers gates hh, hh+128, ...)
  float wix = dWih[hh];
  float wiy = dWih[hh + 128];
  float wiz = dWih[hh + 256];
  float wiw = dWih[hh + 384];
  float fcbv  = fcb[0];
  sh[q4][hh] = 0.f; sc[q4][hh] = 0.f; shp[q4][hh] = 0; scp[q4][hh] = 0;
  __syncthreads();

  // ---------- decoder (4 barriers/step) ----------
  for (int step = 0; step < T_; ++step) {
    // S0: u[h4] partial over z-cols p4*64..+64, rotated segment order;
    //     butterfly reduce in-wave; write packed su2[bg][h4>>1]
    #pragma unroll 1
    for (int bg = 0; bg < BPB; ++bg) {
      const u32* bs = (p4 < 2) ? (const u32*)shp[bg] + (p4 & 1) * 32
                               : (const u32*)scp[bg] + (p4 & 1) * 32;
      const uint4* vp = (const uint4*)bs;
      float a0 = 0.f, a1 = 0.f;
      #pragma unroll
      for (int kk = 0; kk < 8; ++kk) {
        int k = (kk + 2 * p4) & 7;
        uint4 v = vp[k];
        a0 = dot2h(wtpU[4*kk+0], v.x, a0);
        a1 = dot2h(wtpU[4*kk+1], v.y, a1);
        a0 = dot2h(wtpU[4*kk+2], v.z, a0);
        a1 = dot2h(wtpU[4*kk+3], v.w, a1);
      }
      float a = a0 + a1;
      a += __shfl_xor(a, 1, 64);
      a += __shfl_xor(a, 2, 64);          // all 4 lanes now hold u[h4]
      float b = __shfl_xor(a, 4, 64);     // partner row h4^1
      if ((tid & 7) == 0) su2[bg][h4 >> 1] = pkh2(a, b);
    }
    __syncthreads();
    // S2: score partials, packed fp16: thread (t=hh<100, quad q4), 32 h each
    if (hh < T_) {
      const uint2* wp  = (const uint2*)(sw2p + q4 * 16);
      const uint2* e0p = (const uint2*)(&sE1[0][hh * TS + q4 * 32]);
      const uint2* e1p = (const uint2*)(&sE1[1][hh * TS + q4 * 32]);
      const uint2* e2p = (const uint2*)(&sE1[2][hh * TS + q4 * 32]);
      const uint2* e3p = (const uint2*)(&sE1[3][hh * TS + q4 * 32]);
      const uint2* u0p = (const uint2*)(su2[0] + q4 * 16);
      const uint2* u1p = (const uint2*)(su2[1] + q4 * 16);
      const uint2* u2p = (const uint2*)(su2[2] + q4 * 16);
      const uint2* u3p = (const uint2*)(su2[3] + q4 * 16);
      float ac0 = 0.f, ac1 = 0.f, ac2 = 0.f, ac3 = 0.f;
      #pragma unroll
      for (int j = 0; j < 8; ++j) {
        uint2 w2v = wp[j];
        uint2 ev, uv;
        ev = e0p[j]; uv = u0p[j];
        ac0 = dot2h(w2v.x, tanhpk(ev.x, uv.x), ac0);
        ac0 = dot2h(w2v.y, tanhpk(ev.y, uv.y), ac0);
        ev = e1p[j]; uv = u1p[j];
        ac1 = dot2h(w2v.x, tanhpk(ev.x, uv.x), ac1);
        ac1 = dot2h(w2v.y, tanhpk(ev.y, uv.y), ac1);
        ev = e2p[j]; uv = u2p[j];
        ac2 = dot2h(w2v.x, tanhpk(ev.x, uv.x), ac2);
        ac2 = dot2h(w2v.y, tanhpk(ev.y, uv.y), ac2);
        ev = e3p[j]; uv = u3p[j];
        ac3 = dot2h(w2v.x, tanhpk(ev.x, uv.x), ac3);
        ac3 = dot2h(w2v.y, tanhpk(ev.y, uv.y), ac3);
      }
      spart[0][hh * 4 + q4] = ac0;
      spart[1][hh * 4 + q4] = ac1;
      spart[2][hh * 4 + q4] = ac2;
      spart[3][hh * 4 + q4] = ac3;
    }
    __syncthreads();
    // S3: softmax + y for THIS thread's quad only (bg=q4, 2-way redundant).
    //     yv flows to S7 in-register; y-term removed from S6 (rank-1 move).
    float yv;
    {
      const int bg = q4;
      float4 p0 = ((const float4*)spart[bg])[lane];
      float e0 = __expf((p0.x + p0.y) + (p0.z + p0.w));
      float es = e0, ys = e0 * sye[bg][lane];
      if (lane < 36) {
        float4 p1 = ((const float4*)spart[bg])[64 + lane];
        float e1 = __expf((p1.x + p1.y) + (p1.z + p1.w));
        es += e1; ys += e1 * sye[bg][64 + lane];
      }
      es = wsum(es); ys = wsum(ys);
      yv = ys * rcpf_(es) + fcbv;
    }
    // S6: gates (no y-term; injected in S7)
    #pragma unroll 1
    for (int bg = 0; bg < BPB; ++bg) {
      const uint4* hr = (const uint4*)(const u32*)shp[bg];
      float a0 = biasD, a1 = 0.f, a2 = 0.f, a3 = 0.f;
      #pragma unroll
      for (int k = 0; k < 16; ++k) {
        uint4 hv = hr[k];
        a0 = dot2h(wpkD[4*k+0], hv.x, a0);
        a1 = dot2h(wpkD[4*k+1], hv.y, a1);
        a2 = dot2h(wpkD[4*k+2], hv.z, a2);
        a3 = dot2h(wpkD[4*k+3], hv.w, a3);
      }
      sg[bg][tid] = (a0 + a1) + (a2 + a3);
    }
    __syncthreads();
    // S7: pointwise LSTM with y-injection (all 4 batches, full block)
    {
      float gi = sigm(sg[q4][hh]        + wix * yv);
      float gf = sigm(sg[q4][hh + 128]  + wiy * yv);
      float gg = tanh_(sg[q4][hh + 256] + wiz * yv);
      float go = sigm(sg[q4][hh + 384]  + wiw * yv);
      float c  = gf * sc[q4][hh] + gi * gg;
      sc[q4][hh] = c;
      float d  = go * tanh_(c);
      sh[q4][hh] = d;
      shp[q4][hh] = f2h(d);
      scp[q4][hh] = f2h(c);
    }
    __syncthreads();
  }

  // ---------- final beta -> ctx -> head ----------
  if (wv < BPB) {                     // wave w computes beta for batch w
    int bg = wv;
    float4 p0 = ((const float4*)spart[bg])[lane];
    float e0 = __expf((p0.x + p0.y) + (p0.z + p0.w));
    float e1 = 0.f;
    if (lane < 36) {
      float4 p1 = ((const float4*)spart[bg])[64 + lane];
      e1 = __expf((p1.x + p1.y) + (p1.z + p1.w));
    }
    float iv = rcpf_(wsum(e0 + e1));
    sye[bg][lane] = e0 * iv;          // overwrite ye with beta
    if (lane < 36) sye[bg][64 + lane] = e1 * iv;
  }
  __syncthreads();
  {
    const u16* xeb = qws + (size_t)(b0 + q4) * QS + hh;
    float cx = 0.f;
    #pragma unroll 4
    for (int t = 0; t < T_; ++t)
      cx += sye[q4][t] * h2f(xeb[t * NT]);
    su[q4][hh] = cx;                  // ctx
  }
  __syncthreads();
  if (tid < BPB * C_) {
    int bg = tid >> 5, cls = tid & 31;
    const float* w = fcfW + (size_t)cls * 256;
    float acc = fcfb[cls];
    #pragma unroll 8
    for (int k = 0; k < 128; ++k)
      acc += w[k] * sh[bg][k] + w[128 + k] * su[bg][k];
    out[(size_t)(b0 + bg) * C_ + cls] = acc;
  }
}

// ================== fallback (R7 structure, no workspace) ==================
__global__ void __launch_bounds__(NT)
darnn_fb(const float* __restrict__ X,
         const float* __restrict__ eWih, const float* __restrict__ eWhh,
         const float* __restrict__ ebih, const float* __restrict__ ebhh,
         const float* __restrict__ eAw,
         const float* __restrict__ dW1,  const float* __restrict__ db1,
         const float* __restrict__ dW2,
         const float* __restrict__ dWih, const float* __restrict__ dWhh,
         const float* __restrict__ dbih, const float* __restrict__ dbhh,
         const float* __restrict__ fcW,  const float* __restrict__ fcb,
         const float* __restrict__ fcfW, const float* __restrict__ fcfb,
         float* __restrict__ out)
{
  __shared__ __align__(16) u16   sxh[12800];
  __shared__ __align__(16) u16   sXe[12800];
  __shared__ __align__(16) float sg[512];
  __shared__ __align__(16) float sh[128];
  __shared__ __align__(16) float sc[128];
  __shared__ __align__(16) u16   shp[128];
  __shared__ __align__(16) u16   scp[128];
  __shared__ __align__(16) float su[128];
  __shared__ __align__(16) float spart[512];
  __shared__ __align__(16) float sscore[128];
  __shared__ __align__(16) float sctx[128];
  __shared__ float sred[8];
  __shared__ float sredY[2];

  const int tid  = threadIdx.x;
  const int lane = tid & 63;
  const int wv   = tid >> 6;
  const int b    = blockIdx.x;
  const int hh   = tid & 127;
  const int q4   = tid >> 7;

  {
    const float4* Xb4 = (const float4*)(X + (size_t)b * 12800);
    u32* dst = (u32*)sxh;
    #pragma unroll
    for (int i = 0; i < 7; ++i) {
      int idx = tid + NT * i;
      if (idx < 3200) {
        float4 v = Xb4[idx];
        dst[2*idx]   = pkh2(v.x, v.y);
        dst[2*idx+1] = pkh2(v.z, v.w);
      }
    }
  }
  __syncthreads();
  float sval = 0.f;
  if (tid < 128) {
    #pragma unroll 4
    for (int t = 0; t < T_; ++t)
      sval += h2f(sxh[t * 128 + tid]) * eAw[256 + t];
  }
  float ee = (tid < 128) ? __expf(sval) : 0.f;
  float sm = wsum(ee);
  if (lane == 0 && wv < 2) sred[2 + wv] = sm;
  __syncthreads();
  if (tid < 128) {
    su[tid] = ee * rcpf_(sred[2] + sred[3]);
    sh[tid] = 0.f; sc[tid] = 0.f; shp[tid] = 0; scp[tid] = 0;
  }
  __syncthreads();
  {
    u32* sx32 = (u32*)sxh;
    #pragma unroll
    for (int i = 0; i < 13; ++i) {
      int p = tid + NT * i;
      if (p < 6400) {
        float lo, hi; unph(sx32[p], lo, hi);
        int m = (2 * p) & 127;
        sx32[p] = pkh2(lo * su[m], hi * su[m + 1]);
      }
    }
  }
  __syncthreads();

  u32 wpkH[64], wpkI[64];
  {
    const float4* wr = (const float4*)(eWhh + (size_t)tid * 128);
    #pragma unroll
    for (int i = 0; i < 32; ++i) {
      float4 v = wr[i];
      wpkH[2*i] = pkh2(v.x, v.y); wpkH[2*i+1] = pkh2(v.z, v.w);
    }
    const float4* wi = (const float4*)(eWih + (size_t)tid * 128);
    #pragma unroll
    for (int i = 0; i < 32; ++i) {
      float4 v = wi[i];
      wpkI[2*i] = pkh2(v.x, v.y); wpkI[2*i+1] = pkh2(v.z, v.w);
    }
  }
  float biasg = ebih[tid] + ebhh[tid];

  for (int t = 0; t < T_; ++t) {
    float a0 = biasg, a1 = 0.f, a2 = 0.f, a3 = 0.f;
    const uint4* hr = (const uint4*)(const u32*)shp;
    #pragma unroll
    for (int k = 0; k < 16; ++k) {
      uint4 hv = hr[k];
      a0 = dot2h(wpkH[4*k+0], hv.x, a0);
      a1 = dot2h(wpkH[4*k+1], hv.y, a1);
      a2 = dot2h(wpkH[4*k+2], hv.z, a2);
      a3 = dot2h(wpkH[4*k+3], hv.w, a3);
    }
    const uint4* xr = (const uint4*)((const u32*)sxh + t * 64);
    #pragma unroll
    for (int k = 0; k < 16; ++k) {
      uint4 xv = xr[k];
      a0 = dot2h(wpkI[4*k+0], xv.x, a0);
      a1 = dot2h(wpkI[4*k+1], xv.y, a1);
      a2 = dot2h(wpkI[4*k+2], xv.z, a2);
      a3 = dot2h(wpkI[4*k+3], xv.w, a3);
    }
    sg[tid] = (a0 + a1) + (a2 + a3);
    __syncthreads();
    if (tid < 128) {
      float gi = sigm(sg[tid]);
      float gf = sigm(sg[tid + 128]);
      float gg = tanh_(sg[tid + 256]);
      float go = sigm(sg[tid + 384]);
      float c  = gf * sc[tid] + gi * gg;
      sc[tid]  = c;
      float h  = go * tanh_(c);
      sh[tid]  = h;
      u16 hb = f2h(h);
      shp[tid] = hb; scp[tid] = f2h(c);
      sXe[t * 128 + tid] = hb;
    }
    __syncthreads();
  }

  {
    u32 wtp[64];
    const float4* w4 = (const float4*)(dW1 + (size_t)hh * 384 + 256);
    #pragma unroll
    for (int i = 0; i < 32; ++i) {
      float4 v = w4[i];
      wtp[2*i] = pkh2(v.x, v.y); wtp[2*i+1] = pkh2(v.z, v.w);
    }
    float b1v = db1[hh];
    u16 e1out[25];
    #pragma unroll 1
    for (int i = 0; i < 25; ++i) {
      int t = q4 * 25 + i;
      const uint4* xe4 = (const uint4*)(sXe + t * 128);
      float a0 = 0.f, a1 = 0.f;
      #pragma unroll
      for (int k = 0; k < 16; ++k) {
        uint4 xv = xe4[k];
        a0 = dot2h(wtp[4*k+0], xv.x, a0);
        a1 = dot2h(wtp[4*k+1], xv.y, a1);
        a0 = dot2h(wtp[4*k+2], xv.z, a0);
        a1 = dot2h(wtp[4*k+3], xv.w, a1);
      }
      e1out[i] = f2h(a0 + a1 + b1v);
    }
    __syncthreads();
    #pragma unroll 1
    for (int i = 0; i < 25; ++i)
      sxh[(q4 * 25 + i) * 128 + hh] = e1out[i];
  }

  u32 wpkD[64];
  {
    const float4* wr = (const float4*)(dWhh + (size_t)tid * 128);
    #pragma unroll
    for (int i = 0; i < 32; ++i) {
      float4 v = wr[i];
      wpkD[2*i] = pkh2(v.x, v.y); wpkD[2*i+1] = pkh2(v.z, v.w);
    }
  }
  u32 wtpU[32];
  {
    const float4* wu = (const float4*)(dW1 + (size_t)hh * 384 + q4 * 64);
    #pragma unroll
    for (int i = 0; i < 16; ++i) {
      float4 v = wu[i];
      wtpU[2*i] = pkh2(v.x, v.y); wtpU[2*i+1] = pkh2(v.z, v.w);
    }
  }
  float biasD = dbih[tid] + dbhh[tid];
  float wihj  = dWih[tid];
  float w2a   = dW2[lane];
  float w2b   = dW2[lane + 64];
  float fcbv  = fcb[0];
  float fcwv  = (tid < 128) ? fcW[tid] : 0.f;
  if (tid < 128) { sh[tid] = 0.f; sc[tid] = 0.f; shp[tid] = 0; scp[tid] = 0; }
  __syncthreads();

  for (int step = 0; step < T_; ++step) {
    {
      const u32* base = (q4 < 2) ? (const u32*)shp : (const u32*)scp;
      const uint4* vp = (const uint4*)(base + (q4 & 1) * 32);
      float a0 = 0.f, a1 = 0.f;
      #pragma unroll
      for (int k = 0; k < 8; ++k) {
        uint4 v = vp[k];
        a0 = dot2h(wtpU[4*k+0], v.x, a0);
        a1 = dot2h(wtpU[4*k+1], v.y, a1);
        a0 = dot2h(wtpU[4*k+2], v.z, a0);
        a1 = dot2h(wtpU[4*k+3], v.w, a1);
      }
      spart[q4 * 128 + hh] = a0 + a1;
    }
    __syncthreads();
    {
      float ul = spart[lane] + spart[128 + lane]
               + spart[256 + lane] + spart[384 + lane];
      float uh = spart[64 + lane] + spart[192 + lane]
               + spart[320 + lane] + spart[448 + lane];
      #pragma unroll 1
      for (int i = 0; i < 13; ++i) {
        int t = wv + 8 * i;
        if (t < T_) {
          float v = w2a * ptanh(h2f(sxh[t * 128 + lane]) + ul)
                  + w2b * ptanh(h2f(sxh[t * 128 + 64 + lane]) + uh);
          v = wsum(v);
          if (lane == 0) sscore[t] = v;
        }
      }
    }
    __syncthreads();
    if (wv == 0) {
      float s0 = sscore[lane];
      float E0 = __expf(s0);
      float E1v = (lane < 36) ? __expf(sscore[lane + 64]) : 0.f;
      float s  = wsum(E0 + E1v);
      float iv = rcpf_(s);
      sscore[lane] = E0 * iv;
      if (lane < 36) sscore[lane + 64] = E1v * iv;
    }
    __syncthreads();
    {
      float pc = 0.f;
      #pragma unroll
      for (int i = 0; i < 25; ++i) {
        int t = q4 * 25 + i;
        pc += sscore[t] * h2f(sXe[t * 128 + hh]);
      }
      spart[q4 * 128 + hh] = pc;
    }
    __syncthreads();
    {
      float v = 0.f;
      if (tid < 128) {
        float cx = spart[tid] + spart[tid + 128]
                 + spart[tid + 256] + spart[tid + 384];
        sctx[tid] = cx;
        v = fcwv * cx;
      }
      v = wsum(v);
      if (lane == 0 && wv < 2) sredY[wv] = v;
    }
    __syncthreads();
    {
      float yt = sredY[0] + sredY[1] + fcbv;
      float a0 = biasD + wihj * yt, a1 = 0.f, a2 = 0.f, a3 = 0.f;
      const uint4* hr = (const uint4*)(const u32*)shp;
      #pragma unroll
      for (int k = 0; k < 16; ++k) {
        uint4 hv = hr[k];
        a0 = dot2h(wpkD[4*k+0], hv.x, a0);
        a1 = dot2h(wpkD[4*k+1], hv.y, a1);
        a2 = dot2h(wpkD[4*k+2], hv.z, a2);
        a3 = dot2h(wpkD[4*k+3], hv.w, a3);
      }
      sg[tid] = (a0 + a1) + (a2 + a3);
    }
    __syncthreads();
    if (tid < 128) {
      float gi = sigm(sg[tid]);
      float gf = sigm(sg[tid + 128]);
      float gg = tanh_(sg[tid + 256]);
      float go = sigm(sg[tid + 384]);
      float c  = gf * sc[tid] + gi * gg;
      sc[tid]  = c;
      float d  = go * tanh_(c);
      sh[tid]  = d;
      shp[tid] = f2h(d);
      scp[tid] = f2h(c);
    }
    __syncthreads();
  }

  if (tid < C_) {
    float acc = fcfb[tid];
    const float* w = fcfW + (size_t)tid * 256;
    #pragma unroll 8
    for (int k = 0; k < 128; ++k)
      acc += w[k] * sh[k] + w[128 + k] * sctx[k];
    out[(size_t)b * C_ + tid] = acc;
  }
}

extern "C" void kernel_launch(void* const* d_in, const int* in_sizes, int n_in,
                              void* d_out, int out_size, void* d_ws, size_t ws_size,
                              hipStream_t stream) {
  (void)n_in; (void)out_size;
  const float* X    = (const float*)d_in[0];
  const float* eWih = (const float*)d_in[1];
  const float* eWhh = (const float*)d_in[2];
  const float* ebih = (const float*)d_in[3];
  const float* ebhh = (const float*)d_in[4];
  const float* eAw  = (const float*)d_in[5];
  const float* eAb  = (const float*)d_in[6];
  const float* dW1  = (const float*)d_in[7];
  const float* db1  = (const float*)d_in[8];
  const float* dW2  = (const float*)d_in[9];
  const float* db2  = (const float*)d_in[10];
  const float* dWih = (const float*)d_in[11];
  const float* dWhh = (const float*)d_in[12];
  const float* dbih = (const float*)d_in[13];
  const float* dbhh = (const float*)d_in[14];
  const float* fcW  = (const float*)d_in[15];
  const float* fcb  = (const float*)d_in[16];
  const float* fcfW = (const float*)d_in[17];
  const float* fcfb = (const float*)d_in[18];
  float* out = (float*)d_out;

  const int B = in_sizes[0] / (T_ * 128);
  const size_t needQ = (size_t)B * QS * sizeof(u16);
  if (ws_size >= needQ && (B % BPB) == 0) {
    darnn4<<<dim3(B / BPB), dim3(NT), 0, stream>>>(
        X, eWih, eWhh, ebih, ebhh, eAw, eAb,
        dW1, db1, dW2, db2, dWih, dWhh, dbih, dbhh,
        fcW, fcb, fcfW, fcfb, (u16*)d_ws, out);
  } else {
    darnn_fb<<<dim3(B), dim3(NT), 0, stream>>>(
        X, eWih, eWhh, ebih, ebhh, eAw,
        dW1, db1, dW2, dWih, dWhh, dbih, dbhh,
        fcW, fcb, fcfW, fcfb, out);
  }
}